// Round 2
// baseline (516.966 us; speedup 1.0000x reference)
//
#include <hip/hip_runtime.h>
#include <stdint.h>

#define S_LEN 2048
#define DMODEL 1024
#define NHEAD 16
#define DHEAD 64
#define NBATCH 2
#define NE 4194304   // NBATCH*S_LEN*DMODEL
#define WN 1048576   // DMODEL*DMODEL

typedef unsigned short u16;
typedef float f32x16 __attribute__((ext_vector_type(16)));
typedef __bf16 bf16x8 __attribute__((ext_vector_type(8)));

__device__ __forceinline__ u16 f2bf(float x) {
  union { float f; unsigned u; } v; v.f = x;
  unsigned r = v.u + 0x7fffu + ((v.u >> 16) & 1u);
  return (u16)(r >> 16);
}
__device__ __forceinline__ unsigned cvt_pk_bf16(float lo, float hi) {
  unsigned r;
  asm("v_cvt_pk_bf16_f32 %0, %1, %2" : "=v"(r) : "v"(lo), "v"(hi));
  return r;
}
__device__ __forceinline__ void gld_lds16(const void* g, void* l) {
  __builtin_amdgcn_global_load_lds(
      (const __attribute__((address_space(1))) unsigned*)g,
      (__attribute__((address_space(3))) unsigned*)l, 16, 0, 0);
}

// ---------------- convert q,k,v f32 -> bf16 ----------------
__global__ __launch_bounds__(256) void cvt_inputs(
    const float* __restrict__ q, const float* __restrict__ k, const float* __restrict__ v,
    u16* __restrict__ xq, u16* __restrict__ xk, u16* __restrict__ xv)
{
  int i = blockIdx.x * 256 + threadIdx.x;
  const int stride = gridDim.x * 256;
  for (; i < NE / 4; i += stride) {
    float4 a = ((const float4*)q)[i];
    float4 b = ((const float4*)k)[i];
    float4 c = ((const float4*)v)[i];
    ushort4 oa, ob, oc;
    oa.x = f2bf(a.x); oa.y = f2bf(a.y); oa.z = f2bf(a.z); oa.w = f2bf(a.w);
    ob.x = f2bf(b.x); ob.y = f2bf(b.y); ob.z = f2bf(b.z); ob.w = f2bf(b.w);
    oc.x = f2bf(c.x); oc.y = f2bf(c.y); oc.z = f2bf(c.z); oc.w = f2bf(c.w);
    ((ushort4*)xq)[i] = oa;
    ((ushort4*)xk)[i] = ob;
    ((ushort4*)xv)[i] = oc;
  }
}

// ---------------- convert + transpose weights: W[k][n] -> WT[n][k] bf16 ----------------
__global__ __launch_bounds__(256) void wtrans(
    const float* __restrict__ Wq, const float* __restrict__ Wk,
    const float* __restrict__ Wv, const float* __restrict__ Wo,
    u16* __restrict__ oq, u16* __restrict__ ok, u16* __restrict__ ov, u16* __restrict__ oo)
{
  __shared__ u16 t[64][65];
  const float* W; u16* O;
  if (blockIdx.z == 0)      { W = Wq; O = oq; }
  else if (blockIdx.z == 1) { W = Wk; O = ok; }
  else if (blockIdx.z == 2) { W = Wv; O = ov; }
  else                      { W = Wo; O = oo; }
  const int tid = threadIdx.x;
  const int r0 = blockIdx.y * 64, c0 = blockIdx.x * 64;
#pragma unroll
  for (int i = 0; i < 4; ++i) {
    const int row = i * 16 + (tid >> 4);
    const int col = (tid & 15) * 4;
    float4 wv = *(const float4*)(W + (size_t)(r0 + row) * DMODEL + c0 + col);
    t[row][col + 0] = f2bf(wv.x);
    t[row][col + 1] = f2bf(wv.y);
    t[row][col + 2] = f2bf(wv.z);
    t[row][col + 3] = f2bf(wv.w);
  }
  __syncthreads();
#pragma unroll
  for (int i = 0; i < 4; ++i) {
    const int row = i * 16 + (tid >> 4);
    const int col = (tid & 15) * 4;
    ushort4 o;
    o.x = t[col + 0][row]; o.y = t[col + 1][row];
    o.z = t[col + 2][row]; o.w = t[col + 3][row];
    *(ushort4*)(O + (size_t)(c0 + row) * DMODEL + r0 + col) = o;
  }
}

// ---------------- 128x128 bf16 MFMA GEMM, B^T input, global_load_lds staging ----------------
template <int OUTMODE>
__device__ __forceinline__ void gemm_core(
    const u16* __restrict__ A, const u16* __restrict__ Bt,
    const float* __restrict__ bias, void* __restrict__ outp,
    float scale, int m0, int n0)
{
  __shared__ u16 As[128 * 32];
  __shared__ u16 Bs[128 * 32];
  const int tid = threadIdx.x;
  const int lane = tid & 63, w = tid >> 6;
  const int q_l = lane & 31, hi = lane >> 5;
  const int wr = w >> 1, wc = w & 1;

  f32x16 acc[2][2];
#pragma unroll
  for (int a = 0; a < 2; ++a)
#pragma unroll
    for (int b = 0; b < 2; ++b)
#pragma unroll
      for (int r = 0; r < 16; ++r) acc[a][b][r] = 0.f;

  const u16* srcA = A + (size_t)(m0 + (tid >> 2)) * DMODEL + (tid & 3) * 8;
  const u16* srcB = Bt + (size_t)(n0 + (tid >> 2)) * DMODEL + (tid & 3) * 8;
  u16* dstA = As + w * 512;
  u16* dstB = Bs + w * 512;

  for (int kt = 0; kt < DMODEL; kt += 32) {
    gld_lds16(srcA + kt, dstA);
    gld_lds16(srcA + kt + (size_t)64 * DMODEL, dstA + 2048);
    gld_lds16(srcB + kt, dstB);
    gld_lds16(srcB + kt + (size_t)64 * DMODEL, dstB + 2048);
    __syncthreads();
#pragma unroll
    for (int kk = 0; kk < 2; ++kk) {
      bf16x8 af[2], bfv[2];
#pragma unroll
      for (int mb = 0; mb < 2; ++mb)
        af[mb] = *reinterpret_cast<const bf16x8*>(&As[(wr * 64 + mb * 32 + q_l) * 32 + kk * 16 + hi * 8]);
#pragma unroll
      for (int nb = 0; nb < 2; ++nb)
        bfv[nb] = *reinterpret_cast<const bf16x8*>(&Bs[(wc * 64 + nb * 32 + q_l) * 32 + kk * 16 + hi * 8]);
#pragma unroll
      for (int mb = 0; mb < 2; ++mb)
#pragma unroll
        for (int nb = 0; nb < 2; ++nb)
          acc[mb][nb] = __builtin_amdgcn_mfma_f32_32x32x16_bf16(af[mb], bfv[nb], acc[mb][nb], 0, 0, 0);
    }
    __syncthreads();
  }

#pragma unroll
  for (int mb = 0; mb < 2; ++mb) {
#pragma unroll
    for (int nb = 0; nb < 2; ++nb) {
      const int n = n0 + wc * 64 + nb * 32 + q_l;
      const float bn = bias[n];
#pragma unroll
      for (int r = 0; r < 16; ++r) {
        const int m = m0 + wr * 64 + mb * 32 + (r & 3) + 8 * (r >> 2) + 4 * hi;
        const float val = (acc[mb][nb][r] + bn) * scale;
        if (OUTMODE == 0) {
          const int bb = m >> 11, s = m & 2047, hh = n >> 6, d = n & 63;
          ((u16*)outp)[(((size_t)(bb * NHEAD + hh)) * S_LEN + s) * DHEAD + d] = f2bf(val);
        } else {
          ((float*)outp)[(size_t)m * DMODEL + n] = val;
        }
      }
    }
  }
}

__global__ __launch_bounds__(256) void gemm_qkv(
    const u16* __restrict__ xq, const u16* __restrict__ xk, const u16* __restrict__ xv,
    const u16* __restrict__ wqt, const u16* __restrict__ wkt, const u16* __restrict__ wvt,
    const float* __restrict__ bq, const float* __restrict__ bk, const float* __restrict__ bv,
    u16* __restrict__ qh, u16* __restrict__ kh, u16* __restrict__ vh)
{
  const u16 *A, *Bt; const float* bias; u16* O; float scale;
  if (blockIdx.z == 0)      { A = xq; Bt = wqt; bias = bq; O = qh; scale = 0.125f; }
  else if (blockIdx.z == 1) { A = xk; Bt = wkt; bias = bk; O = kh; scale = 1.f; }
  else                      { A = xv; Bt = wvt; bias = bv; O = vh; scale = 1.f; }
  gemm_core<0>(A, Bt, bias, O, scale, blockIdx.y * 128, blockIdx.x * 128);
}

__global__ __launch_bounds__(256) void gemm_out(
    const u16* __restrict__ ctx, const u16* __restrict__ wot,
    const float* __restrict__ bo, float* __restrict__ out)
{
  gemm_core<1>(ctx, wot, bo, out, 1.f, blockIdx.y * 128, blockIdx.x * 128);
}

// ---------------- transpose Vh[bh][s][d] -> Vt[bh][d][s] ----------------
__global__ __launch_bounds__(256) void vtrans(const u16* __restrict__ vh, u16* __restrict__ vt)
{
  __shared__ u16 t[64][72];
  const int tid = threadIdx.x;
  const int bh = blockIdx.y;
  const int s0 = blockIdx.x * 64;
  const u16* src = vh + (size_t)bh * S_LEN * DHEAD;
  u16* dst = vt + (size_t)bh * DHEAD * S_LEN;
#pragma unroll
  for (int i = 0; i < 2; ++i) {
    const int row = i * 32 + (tid >> 3);
    const int c8 = (tid & 7) * 8;
    *(uint4*)&t[row][c8] = *(const uint4*)(src + (size_t)(s0 + row) * DHEAD + c8);
  }
  __syncthreads();
#pragma unroll
  for (int i = 0; i < 2; ++i) {
    const int d = i * 32 + (tid >> 3);
    const int c8 = (tid & 7) * 8;
    unsigned p0 = (unsigned)t[c8 + 0][d] | ((unsigned)t[c8 + 1][d] << 16);
    unsigned p1 = (unsigned)t[c8 + 2][d] | ((unsigned)t[c8 + 3][d] << 16);
    unsigned p2 = (unsigned)t[c8 + 4][d] | ((unsigned)t[c8 + 5][d] << 16);
    unsigned p3 = (unsigned)t[c8 + 6][d] | ((unsigned)t[c8 + 7][d] << 16);
    uint4 o; o.x = p0; o.y = p1; o.z = p2; o.w = p3;
    *(uint4*)(dst + (size_t)d * S_LEN + s0 + c8) = o;
  }
}

// ---------------- fused attention v2: recompute-QK, b128 swizzled transpose ----------------
// grid (64 q-blocks, 32 bh), 512 threads (8 waves). Wave w owns k-range [w*256, (w+1)*256).
// Phase 1 computes only the softmax denominator (no P retention -> low VGPR).
// Phase 2 recomputes QK per 32-k tile, normalizes in-register, stores attn f32 via a
// per-wave XOR-swizzled [q][k] LDS tile (4x ds_write_b128 + 4x ds_read_b128, conflict-free),
// and accumulates PV with normalized bf16 fragments (ctx needs no epilogue scale).
__global__ __launch_bounds__(512) void attn_fused(
    const u16* __restrict__ qh, const u16* __restrict__ kh,
    const u16* __restrict__ vt, const float* __restrict__ mask,
    float* __restrict__ attn_out, u16* __restrict__ ctx_out)
{
  __shared__ float smaskv[S_LEN];                    // 8 KB
  __shared__ __align__(16) float sbuf[8][32][32];    // 32 KB, per-wave swizzled [q][k]
  __shared__ float srow[8][32];                      // 1 KB

  const int tid = threadIdx.x;
  const int lane = tid & 63, w = tid >> 6;
  const int q_l = lane & 31, hi = lane >> 5;
  const int qb = blockIdx.x, bh = blockIdx.y;
  const int b = bh >> 4, h = bh & 15;
  const int q0 = qb * 32;

  const u16* Qp = qh + (size_t)bh * S_LEN * DHEAD;
  const u16* Kp = kh + (size_t)bh * S_LEN * DHEAD;
  const u16* Vp = vt + (size_t)bh * DHEAD * S_LEN;

  for (int i = tid; i < S_LEN / 4; i += 512) {
    float4 m4 = ((const float4*)(mask + (size_t)b * S_LEN))[i];
    smaskv[4 * i + 0] = m4.x * -1e9f;
    smaskv[4 * i + 1] = m4.y * -1e9f;
    smaskv[4 * i + 2] = m4.z * -1e9f;
    smaskv[4 * i + 3] = m4.w * -1e9f;
  }
  __syncthreads();

  // Q fragments (B-operand of swapped mfma): lane holds Q[q0+q_l][c*16 + hi*8 + i]
  bf16x8 qf[4];
  {
    const u16* qrow = Qp + (size_t)(q0 + q_l) * DHEAD + hi * 8;
#pragma unroll
    for (int c = 0; c < 4; ++c) qf[c] = *reinterpret_cast<const bf16x8*>(qrow + c * 16);
  }

  const int k0w = w * 256;
  float rsum = 0.f;

  // ---- phase 1: softmax denominator only (K double-buffered) ----
  {
    bf16x8 kc[4], kn[4];
    const u16* krow0 = Kp + (size_t)(k0w + q_l) * DHEAD + hi * 8;
#pragma unroll
    for (int c = 0; c < 4; ++c) kc[c] = *reinterpret_cast<const bf16x8*>(krow0 + c * 16);
#pragma unroll
    for (int t = 0; t < 8; ++t) {
      if (t < 7) {
        const u16* krow = Kp + (size_t)(k0w + (t + 1) * 32 + q_l) * DHEAD + hi * 8;
#pragma unroll
        for (int c = 0; c < 4; ++c) kn[c] = *reinterpret_cast<const bf16x8*>(krow + c * 16);
      }
      f32x16 acc;
#pragma unroll
      for (int r = 0; r < 16; ++r) acc[r] = 0.f;
#pragma unroll
      for (int c = 0; c < 4; ++c)
        acc = __builtin_amdgcn_mfma_f32_32x32x16_bf16(kc[c], qf[c], acc, 0, 0, 0);
      const int k0 = k0w + t * 32;
#pragma unroll
      for (int r = 0; r < 16; ++r) {
        const int kl = (r & 3) + 8 * (r >> 2) + 4 * hi;
        rsum += __expf(acc[r] + smaskv[k0 + kl]);
      }
#pragma unroll
      for (int c = 0; c < 4; ++c) kc[c] = kn[c];
    }
  }

  rsum += __shfl_xor(rsum, 32, 64);
  if (lane < 32) srow[w][lane] = rsum;
  __syncthreads();
  float tot = 0.f;
#pragma unroll
  for (int ww = 0; ww < 8; ++ww) tot += srow[ww][q_l];
  const float inv = 1.0f / tot;   // per-lane, for q = q0 + q_l

  // ---- phase 2: recompute QK, normalize, store attn, accumulate PV ----
  float* arow = attn_out + ((size_t)bh * S_LEN + q0) * S_LEN;
  f32x16 cacc[2];
#pragma unroll
  for (int db = 0; db < 2; ++db)
#pragma unroll
    for (int r = 0; r < 16; ++r) cacc[db][r] = 0.f;

#pragma unroll
  for (int t = 0; t < 8; ++t) {
    const int k0 = k0w + t * 32;
    // issue V loads early (independent of QK chain)
    bf16x8 vf[2][2];
#pragma unroll
    for (int s2 = 0; s2 < 2; ++s2)
#pragma unroll
      for (int db = 0; db < 2; ++db)
        vf[s2][db] = *reinterpret_cast<const bf16x8*>(
            Vp + (size_t)(db * 32 + q_l) * S_LEN + k0 + s2 * 16 + hi * 8);
    // recompute QK tile
    bf16x8 kf[4];
    {
      const u16* krow = Kp + (size_t)(k0 + q_l) * DHEAD + hi * 8;
#pragma unroll
      for (int c = 0; c < 4; ++c) kf[c] = *reinterpret_cast<const bf16x8*>(krow + c * 16);
    }
    f32x16 acc;
#pragma unroll
    for (int r = 0; r < 16; ++r) acc[r] = 0.f;
#pragma unroll
    for (int c = 0; c < 4; ++c)
      acc = __builtin_amdgcn_mfma_f32_32x32x16_bf16(kf[c], qf[c], acc, 0, 0, 0);

    float p[16];
#pragma unroll
    for (int r = 0; r < 16; ++r) {
      const int kl = (r & 3) + 8 * (r >> 2) + 4 * hi;
      p[r] = __expf(acc[r] + smaskv[k0 + kl]) * inv;   // normalized attn value (f32)
    }

    // b128 swizzled LDS write: lane (q_l,hi) owns row q_l, 16B chunk (2g+hi)
#pragma unroll
    for (int g = 0; g < 4; ++g) {
      float4 vv; vv.x = p[4 * g + 0]; vv.y = p[4 * g + 1]; vv.z = p[4 * g + 2]; vv.w = p[4 * g + 3];
      const int c4 = (2 * g + hi) ^ (q_l & 7);
      *(float4*)&sbuf[w][q_l][c4 * 4] = vv;
    }

    // pack normalized P -> bf16 fragments, PV MFMA
    unsigned pk[8];
#pragma unroll
    for (int g = 0; g < 4; ++g) {
      pk[2 * g + 0] = cvt_pk_bf16(p[4 * g + 0], p[4 * g + 1]);
      pk[2 * g + 1] = cvt_pk_bf16(p[4 * g + 2], p[4 * g + 3]);
    }
#pragma unroll
    for (int s2 = 0; s2 < 2; ++s2) {
      unsigned a0 = pk[4 * s2 + 0], b0 = pk[4 * s2 + 2];
      unsigned a1 = pk[4 * s2 + 1], b1 = pk[4 * s2 + 3];
      asm volatile("v_permlane32_swap_b32 %0, %1" : "+v"(a0), "+v"(b0));
      asm volatile("v_permlane32_swap_b32 %0, %1" : "+v"(a1), "+v"(b1));
      uint4 frw; frw.x = a0; frw.y = a1; frw.z = b0; frw.w = b1;
      bf16x8 pa = __builtin_bit_cast(bf16x8, frw);
#pragma unroll
      for (int db = 0; db < 2; ++db)
        cacc[db] = __builtin_amdgcn_mfma_f32_32x32x16_bf16(pa, vf[s2][db], cacc[db], 0, 0, 0);
    }

    // b128 swizzled LDS read + coalesced f32 store (8 lanes -> one 128B row segment)
#pragma unroll
    for (int j = 0; j < 4; ++j) {
      const int row = j * 8 + (lane >> 3);
      const int c4 = (lane & 7) ^ (row & 7);
      float4 vv = *(const float4*)&sbuf[w][row][c4 * 4];
      *(float4*)(arow + (size_t)row * S_LEN + k0 + (lane & 7) * 4) = vv;
    }
  }

  // ---- cross-wave ctx reduction (sbuf reused as 32x64 f32 scratch) ----
  __syncthreads();
  float* sred = &sbuf[0][0][0];   // 2048 floats = 8 KB
  for (int i = tid; i < 32 * 64; i += 512) sred[i] = 0.f;
  __syncthreads();
#pragma unroll
  for (int db = 0; db < 2; ++db)
#pragma unroll
    for (int r = 0; r < 16; ++r) {
      const int qq = (r & 3) + 8 * (r >> 2) + 4 * hi;
      atomicAdd(&sred[qq * 64 + db * 32 + q_l], cacc[db][r]);
    }
  __syncthreads();
  {
    const int row = tid >> 4;
    const int d0 = (tid & 15) * 4;
    ushort4 o;
    o.x = f2bf(sred[row * 64 + d0 + 0]);
    o.y = f2bf(sred[row * 64 + d0 + 1]);
    o.z = f2bf(sred[row * 64 + d0 + 2]);
    o.w = f2bf(sred[row * 64 + d0 + 3]);
    *(ushort4*)(ctx_out + (((size_t)(b * S_LEN + q0 + row)) * DMODEL + h * DHEAD + d0)) = o;
  }
}

extern "C" void kernel_launch(void* const* d_in, const int* in_sizes, int n_in,
                              void* d_out, int out_size, void* d_ws, size_t ws_size,
                              hipStream_t stream)
{
  (void)in_sizes; (void)n_in; (void)out_size; (void)ws_size;
  const float* v    = (const float*)d_in[0];
  const float* k    = (const float*)d_in[1];
  const float* q    = (const float*)d_in[2];
  const float* mask = (const float*)d_in[3];
  const float* Wq   = (const float*)d_in[4];
  const float* bq   = (const float*)d_in[5];
  const float* Wk   = (const float*)d_in[6];
  const float* bk   = (const float*)d_in[7];
  const float* Wv   = (const float*)d_in[8];
  const float* bv   = (const float*)d_in[9];
  const float* Wo   = (const float*)d_in[10];
  const float* bo   = (const float*)d_in[11];

  u16* ws16 = (u16*)d_ws;
  u16* xq  = ws16;
  u16* xk  = ws16 + (size_t)1 * NE;
  u16* xv  = ws16 + (size_t)2 * NE;
  u16* qh  = ws16 + (size_t)3 * NE;
  u16* kh  = ws16 + (size_t)4 * NE;
  u16* vh  = ws16 + (size_t)5 * NE;
  u16* wqt = ws16 + (size_t)6 * NE;
  u16* wkt = wqt + WN;
  u16* wvt = wkt + WN;
  u16* wot = wvt + WN;
  u16* vt  = xq;   // alias: xq dead after gemm_qkv
  u16* ctx = xk;   // alias: xk dead after gemm_qkv

  float* outp  = (float*)d_out;
  float* attnp = outp + (size_t)NE;

  cvt_inputs<<<dim3(1024), dim3(256), 0, stream>>>(q, k, v, xq, xk, xv);
  wtrans<<<dim3(16, 16, 4), dim3(256), 0, stream>>>(Wq, Wk, Wv, Wo, wqt, wkt, wvt, wot);
  gemm_qkv<<<dim3(8, 32, 3), dim3(256), 0, stream>>>(xq, xk, xv, wqt, wkt, wvt,
                                                     bq, bk, bv, qh, kh, vh);
  vtrans<<<dim3(32, 32), dim3(256), 0, stream>>>(vh, vt);
  attn_fused<<<dim3(64, 32), dim3(512), 0, stream>>>(qh, kh, vt, mask, attnp, ctx);
  gemm_out<<<dim3(8, 32), dim3(256), 0, stream>>>(ctx, wot, bo, outp);
}

// Round 3
// 437.259 us; speedup vs baseline: 1.1823x; 1.1823x over previous
//
#include <hip/hip_runtime.h>
#include <stdint.h>

#define S_LEN 2048
#define DMODEL 1024
#define NHEAD 16
#define DHEAD 64
#define NBATCH 2
#define NE 4194304   // NBATCH*S_LEN*DMODEL
#define WN 1048576   // DMODEL*DMODEL

typedef unsigned short u16;
typedef float f32x16 __attribute__((ext_vector_type(16)));
typedef __bf16 bf16x8 __attribute__((ext_vector_type(8)));

__device__ __forceinline__ u16 f2bf(float x) {
  union { float f; unsigned u; } v; v.f = x;
  unsigned r = v.u + 0x7fffu + ((v.u >> 16) & 1u);
  return (u16)(r >> 16);
}
__device__ __forceinline__ unsigned cvt_pk_bf16(float lo, float hi) {
  unsigned r;
  asm("v_cvt_pk_bf16_f32 %0, %1, %2" : "=v"(r) : "v"(lo), "v"(hi));
  return r;
}
__device__ __forceinline__ void gld_lds16(const void* g, void* l) {
  __builtin_amdgcn_global_load_lds(
      (const __attribute__((address_space(1))) unsigned*)g,
      (__attribute__((address_space(3))) unsigned*)l, 16, 0, 0);
}

// ---------------- convert q,k,v f32 -> bf16 ----------------
__global__ __launch_bounds__(256) void cvt_inputs(
    const float* __restrict__ q, const float* __restrict__ k, const float* __restrict__ v,
    u16* __restrict__ xq, u16* __restrict__ xk, u16* __restrict__ xv)
{
  int i = blockIdx.x * 256 + threadIdx.x;
  const int stride = gridDim.x * 256;
  for (; i < NE / 4; i += stride) {
    float4 a = ((const float4*)q)[i];
    float4 b = ((const float4*)k)[i];
    float4 c = ((const float4*)v)[i];
    ushort4 oa, ob, oc;
    oa.x = f2bf(a.x); oa.y = f2bf(a.y); oa.z = f2bf(a.z); oa.w = f2bf(a.w);
    ob.x = f2bf(b.x); ob.y = f2bf(b.y); ob.z = f2bf(b.z); ob.w = f2bf(b.w);
    oc.x = f2bf(c.x); oc.y = f2bf(c.y); oc.z = f2bf(c.z); oc.w = f2bf(c.w);
    ((ushort4*)xq)[i] = oa;
    ((ushort4*)xk)[i] = ob;
    ((ushort4*)xv)[i] = oc;
  }
}

// ---------------- convert + transpose weights: W[k][n] -> WT[n][k] bf16 ----------------
__global__ __launch_bounds__(256) void wtrans(
    const float* __restrict__ Wq, const float* __restrict__ Wk,
    const float* __restrict__ Wv, const float* __restrict__ Wo,
    u16* __restrict__ oq, u16* __restrict__ ok, u16* __restrict__ ov, u16* __restrict__ oo)
{
  __shared__ u16 t[64][65];
  const float* W; u16* O;
  if (blockIdx.z == 0)      { W = Wq; O = oq; }
  else if (blockIdx.z == 1) { W = Wk; O = ok; }
  else if (blockIdx.z == 2) { W = Wv; O = ov; }
  else                      { W = Wo; O = oo; }
  const int tid = threadIdx.x;
  const int r0 = blockIdx.y * 64, c0 = blockIdx.x * 64;
#pragma unroll
  for (int i = 0; i < 4; ++i) {
    const int row = i * 16 + (tid >> 4);
    const int col = (tid & 15) * 4;
    float4 wv = *(const float4*)(W + (size_t)(r0 + row) * DMODEL + c0 + col);
    t[row][col + 0] = f2bf(wv.x);
    t[row][col + 1] = f2bf(wv.y);
    t[row][col + 2] = f2bf(wv.z);
    t[row][col + 3] = f2bf(wv.w);
  }
  __syncthreads();
#pragma unroll
  for (int i = 0; i < 4; ++i) {
    const int row = i * 16 + (tid >> 4);
    const int col = (tid & 15) * 4;
    ushort4 o;
    o.x = t[col + 0][row]; o.y = t[col + 1][row];
    o.z = t[col + 2][row]; o.w = t[col + 3][row];
    *(ushort4*)(O + (size_t)(c0 + row) * DMODEL + r0 + col) = o;
  }
}

// ---------------- 128x128 bf16 MFMA GEMM, B^T input, global_load_lds staging ----------------
template <int OUTMODE>
__device__ __forceinline__ void gemm_core(
    const u16* __restrict__ A, const u16* __restrict__ Bt,
    const float* __restrict__ bias, void* __restrict__ outp,
    float scale, int m0, int n0)
{
  __shared__ u16 As[128 * 32];
  __shared__ u16 Bs[128 * 32];
  const int tid = threadIdx.x;
  const int lane = tid & 63, w = tid >> 6;
  const int q_l = lane & 31, hi = lane >> 5;
  const int wr = w >> 1, wc = w & 1;

  f32x16 acc[2][2];
#pragma unroll
  for (int a = 0; a < 2; ++a)
#pragma unroll
    for (int b = 0; b < 2; ++b)
#pragma unroll
      for (int r = 0; r < 16; ++r) acc[a][b][r] = 0.f;

  const u16* srcA = A + (size_t)(m0 + (tid >> 2)) * DMODEL + (tid & 3) * 8;
  const u16* srcB = Bt + (size_t)(n0 + (tid >> 2)) * DMODEL + (tid & 3) * 8;
  u16* dstA = As + w * 512;
  u16* dstB = Bs + w * 512;

  for (int kt = 0; kt < DMODEL; kt += 32) {
    gld_lds16(srcA + kt, dstA);
    gld_lds16(srcA + kt + (size_t)64 * DMODEL, dstA + 2048);
    gld_lds16(srcB + kt, dstB);
    gld_lds16(srcB + kt + (size_t)64 * DMODEL, dstB + 2048);
    __syncthreads();
#pragma unroll
    for (int kk = 0; kk < 2; ++kk) {
      bf16x8 af[2], bfv[2];
#pragma unroll
      for (int mb = 0; mb < 2; ++mb)
        af[mb] = *reinterpret_cast<const bf16x8*>(&As[(wr * 64 + mb * 32 + q_l) * 32 + kk * 16 + hi * 8]);
#pragma unroll
      for (int nb = 0; nb < 2; ++nb)
        bfv[nb] = *reinterpret_cast<const bf16x8*>(&Bs[(wc * 64 + nb * 32 + q_l) * 32 + kk * 16 + hi * 8]);
#pragma unroll
      for (int mb = 0; mb < 2; ++mb)
#pragma unroll
        for (int nb = 0; nb < 2; ++nb)
          acc[mb][nb] = __builtin_amdgcn_mfma_f32_32x32x16_bf16(af[mb], bfv[nb], acc[mb][nb], 0, 0, 0);
    }
    __syncthreads();
  }

#pragma unroll
  for (int mb = 0; mb < 2; ++mb) {
#pragma unroll
    for (int nb = 0; nb < 2; ++nb) {
      const int n = n0 + wc * 64 + nb * 32 + q_l;
      const float bn = bias[n];
#pragma unroll
      for (int r = 0; r < 16; ++r) {
        const int m = m0 + wr * 64 + mb * 32 + (r & 3) + 8 * (r >> 2) + 4 * hi;
        const float val = (acc[mb][nb][r] + bn) * scale;
        if (OUTMODE == 0) {
          const int bb = m >> 11, s = m & 2047, hh = n >> 6, d = n & 63;
          ((u16*)outp)[(((size_t)(bb * NHEAD + hh)) * S_LEN + s) * DHEAD + d] = f2bf(val);
        } else {
          ((float*)outp)[(size_t)m * DMODEL + n] = val;
        }
      }
    }
  }
}

__global__ __launch_bounds__(256) void gemm_qkv(
    const u16* __restrict__ xq, const u16* __restrict__ xk, const u16* __restrict__ xv,
    const u16* __restrict__ wqt, const u16* __restrict__ wkt, const u16* __restrict__ wvt,
    const float* __restrict__ bq, const float* __restrict__ bk, const float* __restrict__ bv,
    u16* __restrict__ qh, u16* __restrict__ kh, u16* __restrict__ vh)
{
  const u16 *A, *Bt; const float* bias; u16* O; float scale;
  if (blockIdx.z == 0)      { A = xq; Bt = wqt; bias = bq; O = qh; scale = 0.125f; }
  else if (blockIdx.z == 1) { A = xk; Bt = wkt; bias = bk; O = kh; scale = 1.f; }
  else                      { A = xv; Bt = wvt; bias = bv; O = vh; scale = 1.f; }
  gemm_core<0>(A, Bt, bias, O, scale, blockIdx.y * 128, blockIdx.x * 128);
}

__global__ __launch_bounds__(256) void gemm_out(
    const u16* __restrict__ ctx, const u16* __restrict__ wot,
    const float* __restrict__ bo, float* __restrict__ out)
{
  gemm_core<1>(ctx, wot, bo, out, 1.f, blockIdx.y * 128, blockIdx.x * 128);
}

// ---------------- transpose Vh[bh][s][d] -> Vt[bh][d][s] ----------------
__global__ __launch_bounds__(256) void vtrans(const u16* __restrict__ vh, u16* __restrict__ vt)
{
  __shared__ u16 t[64][72];
  const int tid = threadIdx.x;
  const int bh = blockIdx.y;
  const int s0 = blockIdx.x * 64;
  const u16* src = vh + (size_t)bh * S_LEN * DHEAD;
  u16* dst = vt + (size_t)bh * DHEAD * S_LEN;
#pragma unroll
  for (int i = 0; i < 2; ++i) {
    const int row = i * 32 + (tid >> 3);
    const int c8 = (tid & 7) * 8;
    *(uint4*)&t[row][c8] = *(const uint4*)(src + (size_t)(s0 + row) * DHEAD + c8);
  }
  __syncthreads();
#pragma unroll
  for (int i = 0; i < 2; ++i) {
    const int d = i * 32 + (tid >> 3);
    const int c8 = (tid & 7) * 8;
    unsigned p0 = (unsigned)t[c8 + 0][d] | ((unsigned)t[c8 + 1][d] << 16);
    unsigned p1 = (unsigned)t[c8 + 2][d] | ((unsigned)t[c8 + 3][d] << 16);
    unsigned p2 = (unsigned)t[c8 + 4][d] | ((unsigned)t[c8 + 5][d] << 16);
    unsigned p3 = (unsigned)t[c8 + 6][d] | ((unsigned)t[c8 + 7][d] << 16);
    uint4 o; o.x = p0; o.y = p1; o.z = p2; o.w = p3;
    *(uint4*)(dst + (size_t)d * S_LEN + s0 + c8) = o;
  }
}

// ---------------- attn kernel A: softmax denominator + unnormalized PV ----------------
// grid (64 qb, 32 bh), 256 threads = 4 waves; wave w owns k in [w*512, (w+1)*512).
// Swapped QK (mfma(K,Q)): lane owns q-column, denominator is in-lane sum.
// PV accumulated unnormalized (online), cross-wave reduce via LDS atomics,
// scaled by inv at the ctx write. inv written to global for kernel B.
__global__ __launch_bounds__(256) void attn_pv(
    const u16* __restrict__ qh, const u16* __restrict__ kh,
    const u16* __restrict__ vt, const float* __restrict__ mask,
    float* __restrict__ inv_g, u16* __restrict__ ctx_out)
{
  __shared__ float smaskv[S_LEN];   // 8 KB
  __shared__ float sred[32][64];    // 8 KB
  __shared__ float srow[4][32];
  __shared__ float sinv[32];

  const int tid = threadIdx.x;
  const int lane = tid & 63, w = tid >> 6;
  const int q_l = lane & 31, hi = lane >> 5;
  const int qb = blockIdx.x, bh = blockIdx.y;
  const int b = bh >> 4, h = bh & 15;
  const int q0 = qb * 32;

  const u16* Qp = qh + (size_t)bh * S_LEN * DHEAD;
  const u16* Kp = kh + (size_t)bh * S_LEN * DHEAD;
  const u16* Vp = vt + (size_t)bh * DHEAD * S_LEN;

  for (int i = tid; i < S_LEN / 4; i += 256) {
    float4 m4 = ((const float4*)(mask + (size_t)b * S_LEN))[i];
    smaskv[4 * i + 0] = m4.x * -1e9f;
    smaskv[4 * i + 1] = m4.y * -1e9f;
    smaskv[4 * i + 2] = m4.z * -1e9f;
    smaskv[4 * i + 3] = m4.w * -1e9f;
  }
  for (int i = tid; i < 32 * 64; i += 256) (&sred[0][0])[i] = 0.f;
  __syncthreads();

  bf16x8 qf[4];
  {
    const u16* qrow = Qp + (size_t)(q0 + q_l) * DHEAD + hi * 8;
#pragma unroll
    for (int c = 0; c < 4; ++c) qf[c] = *reinterpret_cast<const bf16x8*>(qrow + c * 16);
  }

  const int k0w = w * 512;
  float rsum = 0.f;
  f32x16 cacc[2];
#pragma unroll
  for (int db = 0; db < 2; ++db)
#pragma unroll
    for (int r = 0; r < 16; ++r) cacc[db][r] = 0.f;

  bf16x8 kc[4], kn[4];
  {
    const u16* kr0 = Kp + (size_t)(k0w + q_l) * DHEAD + hi * 8;
#pragma unroll
    for (int c = 0; c < 4; ++c) kc[c] = *reinterpret_cast<const bf16x8*>(kr0 + c * 16);
  }

#pragma unroll
  for (int t = 0; t < 16; ++t) {
    if (t < 15) {
      const u16* krow = Kp + (size_t)(k0w + (t + 1) * 32 + q_l) * DHEAD + hi * 8;
#pragma unroll
      for (int c = 0; c < 4; ++c) kn[c] = *reinterpret_cast<const bf16x8*>(krow + c * 16);
    }
    const int k0 = k0w + t * 32;
    bf16x8 vf[2][2];
#pragma unroll
    for (int s2 = 0; s2 < 2; ++s2)
#pragma unroll
      for (int db = 0; db < 2; ++db)
        vf[s2][db] = *reinterpret_cast<const bf16x8*>(
            Vp + (size_t)(db * 32 + q_l) * S_LEN + k0 + s2 * 16 + hi * 8);
    f32x16 acc;
#pragma unroll
    for (int r = 0; r < 16; ++r) acc[r] = 0.f;
#pragma unroll
    for (int c = 0; c < 4; ++c)
      acc = __builtin_amdgcn_mfma_f32_32x32x16_bf16(kc[c], qf[c], acc, 0, 0, 0);
    float p[16];
#pragma unroll
    for (int r = 0; r < 16; ++r) {
      const int kl = (r & 3) + 8 * (r >> 2) + 4 * hi;
      p[r] = __expf(acc[r] + smaskv[k0 + kl]);
      rsum += p[r];
    }
    unsigned pk[8];
#pragma unroll
    for (int g = 0; g < 4; ++g) {
      pk[2 * g + 0] = cvt_pk_bf16(p[4 * g + 0], p[4 * g + 1]);
      pk[2 * g + 1] = cvt_pk_bf16(p[4 * g + 2], p[4 * g + 3]);
    }
#pragma unroll
    for (int s2 = 0; s2 < 2; ++s2) {
      unsigned a0 = pk[4 * s2 + 0], b0 = pk[4 * s2 + 2];
      unsigned a1 = pk[4 * s2 + 1], b1 = pk[4 * s2 + 3];
      asm volatile("v_permlane32_swap_b32 %0, %1" : "+v"(a0), "+v"(b0));
      asm volatile("v_permlane32_swap_b32 %0, %1" : "+v"(a1), "+v"(b1));
      uint4 frw; frw.x = a0; frw.y = a1; frw.z = b0; frw.w = b1;
      bf16x8 pa = __builtin_bit_cast(bf16x8, frw);
#pragma unroll
      for (int db = 0; db < 2; ++db)
        cacc[db] = __builtin_amdgcn_mfma_f32_32x32x16_bf16(pa, vf[s2][db], cacc[db], 0, 0, 0);
    }
#pragma unroll
    for (int c = 0; c < 4; ++c) kc[c] = kn[c];
  }

  rsum += __shfl_xor(rsum, 32, 64);
  if (lane < 32) srow[w][lane] = rsum;
  __syncthreads();
  const float tot = srow[0][q_l] + srow[1][q_l] + srow[2][q_l] + srow[3][q_l];
  const float inv = 1.0f / tot;
  if (w == 0 && lane < 32) {
    sinv[lane] = inv;
    inv_g[(size_t)bh * S_LEN + q0 + lane] = inv;
  }
#pragma unroll
  for (int db = 0; db < 2; ++db)
#pragma unroll
    for (int r = 0; r < 16; ++r) {
      const int qq = (r & 3) + 8 * (r >> 2) + 4 * hi;
      atomicAdd(&sred[qq][db * 32 + q_l], cacc[db][r]);
    }
  __syncthreads();
  {
    const int row = tid >> 3;
    const int d0 = (tid & 7) * 8;
    const float iv = sinv[row];
    union { u16 us[8]; uint4 v; } ou;
#pragma unroll
    for (int j = 0; j < 8; ++j) ou.us[j] = f2bf(sred[row][d0 + j] * iv);
    *(uint4*)(ctx_out + (((size_t)(b * S_LEN + q0 + row)) * DMODEL + h * DHEAD + d0)) = ou.v;
  }
}

// ---------------- attn kernel B: recompute QK (unswapped), write normalized attn ----------------
// grid (64 qb, 32 bh), 256 threads = 4 waves; wave w owns k in [w*512, (w+1)*512).
// Unswapped mfma(Q,K): C col = lane&31 = k index -> each register's 32 lanes store one
// contiguous 128B row segment of attn. No LDS, no barriers, pure streaming writes.
__global__ __launch_bounds__(256) void attn_store(
    const u16* __restrict__ qh, const u16* __restrict__ kh,
    const float* __restrict__ mask, const float* __restrict__ inv_g,
    float* __restrict__ attn_out)
{
  const int tid = threadIdx.x;
  const int lane = tid & 63, w = tid >> 6;
  const int q_l = lane & 31, hi = lane >> 5;
  const int qb = blockIdx.x, bh = blockIdx.y;
  const int b = bh >> 4;
  const int q0 = qb * 32;

  const u16* Qp = qh + (size_t)bh * S_LEN * DHEAD;
  const u16* Kp = kh + (size_t)bh * S_LEN * DHEAD;

  bf16x8 qf[4];
  {
    const u16* qrow = Qp + (size_t)(q0 + q_l) * DHEAD + hi * 8;
#pragma unroll
    for (int c = 0; c < 4; ++c) qf[c] = *reinterpret_cast<const bf16x8*>(qrow + c * 16);
  }

  float myinv[16];
#pragma unroll
  for (int r = 0; r < 16; ++r)
    myinv[r] = inv_g[(size_t)bh * S_LEN + q0 + (r & 3) + 8 * (r >> 2) + 4 * hi];

  const int k0w = w * 512;
  float mval[16];
#pragma unroll
  for (int t = 0; t < 16; ++t)
    mval[t] = mask[(size_t)b * S_LEN + k0w + t * 32 + q_l] * -1e9f;

  float* base = attn_out + ((size_t)bh * S_LEN + q0 + 4 * hi) * S_LEN + k0w + q_l;

  bf16x8 kc[4], kn[4];
  {
    const u16* kr0 = Kp + (size_t)(k0w + q_l) * DHEAD + hi * 8;
#pragma unroll
    for (int c = 0; c < 4; ++c) kc[c] = *reinterpret_cast<const bf16x8*>(kr0 + c * 16);
  }

#pragma unroll
  for (int t = 0; t < 16; ++t) {
    if (t < 15) {
      const u16* krow = Kp + (size_t)(k0w + (t + 1) * 32 + q_l) * DHEAD + hi * 8;
#pragma unroll
      for (int c = 0; c < 4; ++c) kn[c] = *reinterpret_cast<const bf16x8*>(krow + c * 16);
    }
    f32x16 acc;
#pragma unroll
    for (int r = 0; r < 16; ++r) acc[r] = 0.f;
#pragma unroll
    for (int c = 0; c < 4; ++c)
      acc = __builtin_amdgcn_mfma_f32_32x32x16_bf16(qf[c], kc[c], acc, 0, 0, 0);
#pragma unroll
    for (int r = 0; r < 16; ++r) {
      const float pv = __expf(acc[r] + mval[t]) * myinv[r];
      const int rr = (r & 3) + 8 * (r >> 2);
      base[(size_t)rr * S_LEN + t * 32] = pv;
    }
#pragma unroll
    for (int c = 0; c < 4; ++c) kc[c] = kn[c];
  }
}

extern "C" void kernel_launch(void* const* d_in, const int* in_sizes, int n_in,
                              void* d_out, int out_size, void* d_ws, size_t ws_size,
                              hipStream_t stream)
{
  (void)in_sizes; (void)n_in; (void)out_size; (void)ws_size;
  const float* v    = (const float*)d_in[0];
  const float* k    = (const float*)d_in[1];
  const float* q    = (const float*)d_in[2];
  const float* mask = (const float*)d_in[3];
  const float* Wq   = (const float*)d_in[4];
  const float* bq   = (const float*)d_in[5];
  const float* Wk   = (const float*)d_in[6];
  const float* bk   = (const float*)d_in[7];
  const float* Wv   = (const float*)d_in[8];
  const float* bv   = (const float*)d_in[9];
  const float* Wo   = (const float*)d_in[10];
  const float* bo   = (const float*)d_in[11];

  u16* ws16 = (u16*)d_ws;
  u16* xq  = ws16;
  u16* xk  = ws16 + (size_t)1 * NE;
  u16* xv  = ws16 + (size_t)2 * NE;
  u16* qh  = ws16 + (size_t)3 * NE;
  u16* kh  = ws16 + (size_t)4 * NE;
  u16* vh  = ws16 + (size_t)5 * NE;
  u16* wqt = ws16 + (size_t)6 * NE;
  u16* wkt = wqt + WN;
  u16* wvt = wkt + WN;
  u16* wot = wvt + WN;
  float* inv_g = (float*)(wot + WN);   // 32*2048 f32 = 256 KB
  u16* vt  = xq;   // alias: xq dead after gemm_qkv
  u16* ctx = xk;   // alias: xk dead after gemm_qkv

  float* outp  = (float*)d_out;
  float* attnp = outp + (size_t)NE;

  cvt_inputs<<<dim3(1024), dim3(256), 0, stream>>>(q, k, v, xq, xk, xv);
  wtrans<<<dim3(16, 16, 4), dim3(256), 0, stream>>>(Wq, Wk, Wv, Wo, wqt, wkt, wvt, wot);
  gemm_qkv<<<dim3(8, 32, 3), dim3(256), 0, stream>>>(xq, xk, xv, wqt, wkt, wvt,
                                                     bq, bk, bv, qh, kh, vh);
  vtrans<<<dim3(32, 32), dim3(256), 0, stream>>>(vh, vt);
  attn_pv<<<dim3(64, 32), dim3(256), 0, stream>>>(qh, kh, vt, mask, inv_g, ctx);
  attn_store<<<dim3(64, 32), dim3(256), 0, stream>>>(qh, kh, mask, inv_g, attnp);
  gemm_out<<<dim3(8, 32), dim3(256), 0, stream>>>(ctx, wot, bo, outp);
}

// Round 4
// 360.486 us; speedup vs baseline: 1.4341x; 1.2130x over previous
//
#include <hip/hip_runtime.h>
#include <stdint.h>

#define S_LEN 2048
#define DMODEL 1024
#define NHEAD 16
#define DHEAD 64
#define NBATCH 2
#define NE 4194304   // NBATCH*S_LEN*DMODEL
#define WN 1048576   // DMODEL*DMODEL

typedef unsigned short u16;
typedef float f32x16 __attribute__((ext_vector_type(16)));
typedef __bf16 bf16x8 __attribute__((ext_vector_type(8)));

__device__ __forceinline__ u16 f2bf(float x) {
  union { float f; unsigned u; } v; v.f = x;
  unsigned r = v.u + 0x7fffu + ((v.u >> 16) & 1u);
  return (u16)(r >> 16);
}
__device__ __forceinline__ unsigned cvt_pk_bf16(float lo, float hi) {
  unsigned r;
  asm("v_cvt_pk_bf16_f32 %0, %1, %2" : "=v"(r) : "v"(lo), "v"(hi));
  return r;
}
__device__ __forceinline__ void gld_lds16(const void* g, void* l) {
  __builtin_amdgcn_global_load_lds(
      (const __attribute__((address_space(1))) unsigned*)g,
      (__attribute__((address_space(3))) unsigned*)l, 16, 0, 0);
}

// ---------------- convert q,k,v f32 -> bf16 ----------------
__global__ __launch_bounds__(256) void cvt_inputs(
    const float* __restrict__ q, const float* __restrict__ k, const float* __restrict__ v,
    u16* __restrict__ xq, u16* __restrict__ xk, u16* __restrict__ xv)
{
  int i = blockIdx.x * 256 + threadIdx.x;
  const int stride = gridDim.x * 256;
  for (; i < NE / 4; i += stride) {
    float4 a = ((const float4*)q)[i];
    float4 b = ((const float4*)k)[i];
    float4 c = ((const float4*)v)[i];
    ushort4 oa, ob, oc;
    oa.x = f2bf(a.x); oa.y = f2bf(a.y); oa.z = f2bf(a.z); oa.w = f2bf(a.w);
    ob.x = f2bf(b.x); ob.y = f2bf(b.y); ob.z = f2bf(b.z); ob.w = f2bf(b.w);
    oc.x = f2bf(c.x); oc.y = f2bf(c.y); oc.z = f2bf(c.z); oc.w = f2bf(c.w);
    ((ushort4*)xq)[i] = oa;
    ((ushort4*)xk)[i] = ob;
    ((ushort4*)xv)[i] = oc;
  }
}

// ---------------- convert + transpose weights: W[k][n] -> WT[n][k] bf16 ----------------
__global__ __launch_bounds__(256) void wtrans(
    const float* __restrict__ Wq, const float* __restrict__ Wk,
    const float* __restrict__ Wv, const float* __restrict__ Wo,
    u16* __restrict__ oq, u16* __restrict__ ok, u16* __restrict__ ov, u16* __restrict__ oo)
{
  __shared__ u16 t[64][65];
  const float* W; u16* O;
  if (blockIdx.z == 0)      { W = Wq; O = oq; }
  else if (blockIdx.z == 1) { W = Wk; O = ok; }
  else if (blockIdx.z == 2) { W = Wv; O = ov; }
  else                      { W = Wo; O = oo; }
  const int tid = threadIdx.x;
  const int r0 = blockIdx.y * 64, c0 = blockIdx.x * 64;
#pragma unroll
  for (int i = 0; i < 4; ++i) {
    const int row = i * 16 + (tid >> 4);
    const int col = (tid & 15) * 4;
    float4 wv = *(const float4*)(W + (size_t)(r0 + row) * DMODEL + c0 + col);
    t[row][col + 0] = f2bf(wv.x);
    t[row][col + 1] = f2bf(wv.y);
    t[row][col + 2] = f2bf(wv.z);
    t[row][col + 3] = f2bf(wv.w);
  }
  __syncthreads();
#pragma unroll
  for (int i = 0; i < 4; ++i) {
    const int row = i * 16 + (tid >> 4);
    const int col = (tid & 15) * 4;
    ushort4 o;
    o.x = t[col + 0][row]; o.y = t[col + 1][row];
    o.z = t[col + 2][row]; o.w = t[col + 3][row];
    *(ushort4*)(O + (size_t)(c0 + row) * DMODEL + r0 + col) = o;
  }
}

// ---------------- 128x128 bf16 MFMA GEMM, B^T input, global_load_lds staging ----------------
template <int OUTMODE>
__device__ __forceinline__ void gemm_core(
    const u16* __restrict__ A, const u16* __restrict__ Bt,
    const float* __restrict__ bias, void* __restrict__ outp,
    float scale, int m0, int n0)
{
  __shared__ u16 As[128 * 32];
  __shared__ u16 Bs[128 * 32];
  const int tid = threadIdx.x;
  const int lane = tid & 63, w = tid >> 6;
  const int q_l = lane & 31, hi = lane >> 5;
  const int wr = w >> 1, wc = w & 1;

  f32x16 acc[2][2];
#pragma unroll
  for (int a = 0; a < 2; ++a)
#pragma unroll
    for (int b = 0; b < 2; ++b)
#pragma unroll
      for (int r = 0; r < 16; ++r) acc[a][b][r] = 0.f;

  const u16* srcA = A + (size_t)(m0 + (tid >> 2)) * DMODEL + (tid & 3) * 8;
  const u16* srcB = Bt + (size_t)(n0 + (tid >> 2)) * DMODEL + (tid & 3) * 8;
  u16* dstA = As + w * 512;
  u16* dstB = Bs + w * 512;

  for (int kt = 0; kt < DMODEL; kt += 32) {
    gld_lds16(srcA + kt, dstA);
    gld_lds16(srcA + kt + (size_t)64 * DMODEL, dstA + 2048);
    gld_lds16(srcB + kt, dstB);
    gld_lds16(srcB + kt + (size_t)64 * DMODEL, dstB + 2048);
    __syncthreads();
#pragma unroll
    for (int kk = 0; kk < 2; ++kk) {
      bf16x8 af[2], bfv[2];
#pragma unroll
      for (int mb = 0; mb < 2; ++mb)
        af[mb] = *reinterpret_cast<const bf16x8*>(&As[(wr * 64 + mb * 32 + q_l) * 32 + kk * 16 + hi * 8]);
#pragma unroll
      for (int nb = 0; nb < 2; ++nb)
        bfv[nb] = *reinterpret_cast<const bf16x8*>(&Bs[(wc * 64 + nb * 32 + q_l) * 32 + kk * 16 + hi * 8]);
#pragma unroll
      for (int mb = 0; mb < 2; ++mb)
#pragma unroll
        for (int nb = 0; nb < 2; ++nb)
          acc[mb][nb] = __builtin_amdgcn_mfma_f32_32x32x16_bf16(af[mb], bfv[nb], acc[mb][nb], 0, 0, 0);
    }
    __syncthreads();
  }

#pragma unroll
  for (int mb = 0; mb < 2; ++mb) {
#pragma unroll
    for (int nb = 0; nb < 2; ++nb) {
      const int n = n0 + wc * 64 + nb * 32 + q_l;
      const float bn = bias[n];
#pragma unroll
      for (int r = 0; r < 16; ++r) {
        const int m = m0 + wr * 64 + mb * 32 + (r & 3) + 8 * (r >> 2) + 4 * hi;
        const float val = (acc[mb][nb][r] + bn) * scale;
        if (OUTMODE == 0) {
          const int bb = m >> 11, s = m & 2047, hh = n >> 6, d = n & 63;
          ((u16*)outp)[(((size_t)(bb * NHEAD + hh)) * S_LEN + s) * DHEAD + d] = f2bf(val);
        } else {
          ((float*)outp)[(size_t)m * DMODEL + n] = val;
        }
      }
    }
  }
}

__global__ __launch_bounds__(256) void gemm_qkv(
    const u16* __restrict__ xq, const u16* __restrict__ xk, const u16* __restrict__ xv,
    const u16* __restrict__ wqt, const u16* __restrict__ wkt, const u16* __restrict__ wvt,
    const float* __restrict__ bq, const float* __restrict__ bk, const float* __restrict__ bv,
    u16* __restrict__ qh, u16* __restrict__ kh, u16* __restrict__ vh)
{
  const u16 *A, *Bt; const float* bias; u16* O; float scale;
  if (blockIdx.z == 0)      { A = xq; Bt = wqt; bias = bq; O = qh; scale = 0.125f; }
  else if (blockIdx.z == 1) { A = xk; Bt = wkt; bias = bk; O = kh; scale = 1.f; }
  else                      { A = xv; Bt = wvt; bias = bv; O = vh; scale = 1.f; }
  gemm_core<0>(A, Bt, bias, O, scale, blockIdx.y * 128, blockIdx.x * 128);
}

__global__ __launch_bounds__(256) void gemm_out(
    const u16* __restrict__ ctx, const u16* __restrict__ wot,
    const float* __restrict__ bo, float* __restrict__ out)
{
  gemm_core<1>(ctx, wot, bo, out, 1.f, blockIdx.y * 128, blockIdx.x * 128);
}

// ---------------- transpose Vh[bh][s][d] -> Vt[bh][d][s] ----------------
__global__ __launch_bounds__(256) void vtrans(const u16* __restrict__ vh, u16* __restrict__ vt)
{
  __shared__ u16 t[64][72];
  const int tid = threadIdx.x;
  const int bh = blockIdx.y;
  const int s0 = blockIdx.x * 64;
  const u16* src = vh + (size_t)bh * S_LEN * DHEAD;
  u16* dst = vt + (size_t)bh * DHEAD * S_LEN;
#pragma unroll
  for (int i = 0; i < 2; ++i) {
    const int row = i * 32 + (tid >> 3);
    const int c8 = (tid & 7) * 8;
    *(uint4*)&t[row][c8] = *(const uint4*)(src + (size_t)(s0 + row) * DHEAD + c8);
  }
  __syncthreads();
#pragma unroll
  for (int i = 0; i < 2; ++i) {
    const int d = i * 32 + (tid >> 3);
    const int c8 = (tid & 7) * 8;
    unsigned p0 = (unsigned)t[c8 + 0][d] | ((unsigned)t[c8 + 1][d] << 16);
    unsigned p1 = (unsigned)t[c8 + 2][d] | ((unsigned)t[c8 + 3][d] << 16);
    unsigned p2 = (unsigned)t[c8 + 4][d] | ((unsigned)t[c8 + 5][d] << 16);
    unsigned p3 = (unsigned)t[c8 + 6][d] | ((unsigned)t[c8 + 7][d] << 16);
    uint4 o; o.x = p0; o.y = p1; o.z = p2; o.w = p3;
    *(uint4*)(dst + (size_t)d * S_LEN + s0 + c8) = o;
  }
}

// ---------------- attn kernel A v3: per-wave independent q-tile, full k sweep ----------------
// grid (16 qb, 32 bh), 256 threads = 4 waves. Wave w owns q rows [qb*128+w*32, +32),
// sweeps all 64 k-tiles. No barriers after mask stage, no atomics, no cross-wave reduce.
// Swapped QK (mfma(K,Q)): lane col = q, denominator completes in-lane (+1 shfl_xor).
// ctx written per wave; inv distributed to rows via __shfl (bpermute), no LDS.
__global__ __launch_bounds__(256) void attn_pv(
    const u16* __restrict__ qh, const u16* __restrict__ kh,
    const u16* __restrict__ vt, const float* __restrict__ mask,
    float* __restrict__ inv_g, u16* __restrict__ ctx_out)
{
  __shared__ float smaskv[S_LEN];   // 8 KB

  const int tid = threadIdx.x;
  const int lane = tid & 63, w = tid >> 6;
  const int q_l = lane & 31, hi = lane >> 5;
  const int qb = blockIdx.x, bh = blockIdx.y;
  const int b = bh >> 4, h = bh & 15;
  const int q0 = qb * 128 + w * 32;

  const u16* Qp = qh + (size_t)bh * S_LEN * DHEAD;
  const u16* Kp = kh + (size_t)bh * S_LEN * DHEAD;
  const u16* Vp = vt + (size_t)bh * DHEAD * S_LEN;

  for (int i = tid; i < S_LEN / 4; i += 256) {
    float4 m4 = ((const float4*)(mask + (size_t)b * S_LEN))[i];
    smaskv[4 * i + 0] = m4.x * -1e9f;
    smaskv[4 * i + 1] = m4.y * -1e9f;
    smaskv[4 * i + 2] = m4.z * -1e9f;
    smaskv[4 * i + 3] = m4.w * -1e9f;
  }
  __syncthreads();

  bf16x8 qf[4];
  {
    const u16* qrow = Qp + (size_t)(q0 + q_l) * DHEAD + hi * 8;
#pragma unroll
    for (int c = 0; c < 4; ++c) qf[c] = *reinterpret_cast<const bf16x8*>(qrow + c * 16);
  }

  float rsum = 0.f;
  f32x16 cacc[2];
#pragma unroll
  for (int db = 0; db < 2; ++db)
#pragma unroll
    for (int r = 0; r < 16; ++r) cacc[db][r] = 0.f;

  bf16x8 kc[4], kn[4];
  {
    const u16* kr0 = Kp + (size_t)q_l * DHEAD + hi * 8;
#pragma unroll
    for (int c = 0; c < 4; ++c) kc[c] = *reinterpret_cast<const bf16x8*>(kr0 + c * 16);
  }

#pragma unroll 2
  for (int t = 0; t < 64; ++t) {
    const int k0 = t * 32;
    // K prefetch (next tile)
    if (t < 63) {
      const u16* krow = Kp + (size_t)(k0 + 32 + q_l) * DHEAD + hi * 8;
#pragma unroll
      for (int c = 0; c < 4; ++c) kn[c] = *reinterpret_cast<const bf16x8*>(krow + c * 16);
    }
    // V loads issued early; used only at tile end
    bf16x8 vf[2][2];
#pragma unroll
    for (int s2 = 0; s2 < 2; ++s2)
#pragma unroll
      for (int db = 0; db < 2; ++db)
        vf[s2][db] = *reinterpret_cast<const bf16x8*>(
            Vp + (size_t)(db * 32 + q_l) * S_LEN + k0 + s2 * 16 + hi * 8);
    // QK: two independent 2-deep MFMA chains
    f32x16 a0, a1;
#pragma unroll
    for (int r = 0; r < 16; ++r) { a0[r] = 0.f; a1[r] = 0.f; }
    a0 = __builtin_amdgcn_mfma_f32_32x32x16_bf16(kc[0], qf[0], a0, 0, 0, 0);
    a0 = __builtin_amdgcn_mfma_f32_32x32x16_bf16(kc[1], qf[1], a0, 0, 0, 0);
    a1 = __builtin_amdgcn_mfma_f32_32x32x16_bf16(kc[2], qf[2], a1, 0, 0, 0);
    a1 = __builtin_amdgcn_mfma_f32_32x32x16_bf16(kc[3], qf[3], a1, 0, 0, 0);

    float p[16];
#pragma unroll
    for (int g = 0; g < 4; ++g) {
      // rows for r=4g+j are k-local kl = j + 8g + 4hi  -> one b128 mask read
      const float4 mk = *(const float4*)&smaskv[k0 + 8 * g + 4 * hi];
      p[4 * g + 0] = __expf(a0[4 * g + 0] + a1[4 * g + 0] + mk.x);
      p[4 * g + 1] = __expf(a0[4 * g + 1] + a1[4 * g + 1] + mk.y);
      p[4 * g + 2] = __expf(a0[4 * g + 2] + a1[4 * g + 2] + mk.z);
      p[4 * g + 3] = __expf(a0[4 * g + 3] + a1[4 * g + 3] + mk.w);
      rsum += (p[4 * g + 0] + p[4 * g + 1]) + (p[4 * g + 2] + p[4 * g + 3]);
    }
    unsigned pk[8];
#pragma unroll
    for (int g = 0; g < 4; ++g) {
      pk[2 * g + 0] = cvt_pk_bf16(p[4 * g + 0], p[4 * g + 1]);
      pk[2 * g + 1] = cvt_pk_bf16(p[4 * g + 2], p[4 * g + 3]);
    }
#pragma unroll
    for (int s2 = 0; s2 < 2; ++s2) {
      unsigned a0u = pk[4 * s2 + 0], b0u = pk[4 * s2 + 2];
      unsigned a1u = pk[4 * s2 + 1], b1u = pk[4 * s2 + 3];
      asm volatile("v_permlane32_swap_b32 %0, %1" : "+v"(a0u), "+v"(b0u));
      asm volatile("v_permlane32_swap_b32 %0, %1" : "+v"(a1u), "+v"(b1u));
      uint4 frw; frw.x = a0u; frw.y = a1u; frw.z = b0u; frw.w = b1u;
      bf16x8 pa = __builtin_bit_cast(bf16x8, frw);
#pragma unroll
      for (int db = 0; db < 2; ++db)
        cacc[db] = __builtin_amdgcn_mfma_f32_32x32x16_bf16(pa, vf[s2][db], cacc[db], 0, 0, 0);
    }
#pragma unroll
    for (int c = 0; c < 4; ++c) kc[c] = kn[c];
  }

  rsum += __shfl_xor(rsum, 32, 64);
  const float inv = 1.0f / rsum;            // valid on all lanes; lane i (i<32) holds q0+i
  if (lane < 32) inv_g[(size_t)bh * S_LEN + q0 + lane] = inv;

  // distribute inv to the C/D row mapping via bpermute, then direct ctx stores
  float sc[16];
#pragma unroll
  for (int r = 0; r < 16; ++r)
    sc[r] = __shfl(inv, (r & 3) + 8 * (r >> 2) + 4 * hi, 64);
#pragma unroll
  for (int db = 0; db < 2; ++db)
#pragma unroll
    for (int r = 0; r < 16; ++r) {
      const int qq = (r & 3) + 8 * (r >> 2) + 4 * hi;
      ctx_out[((size_t)(b * S_LEN + q0 + qq)) * DMODEL + h * DHEAD + db * 32 + q_l] =
          f2bf(cacc[db][r] * sc[r]);
    }
}

// ---------------- attn kernel B: recompute QK (unswapped), write normalized attn ----------------
// grid (64 qb, 32 bh), 256 threads = 4 waves; wave w owns k in [w*512, (w+1)*512).
// Unswapped mfma(Q,K): C col = lane&31 = k index -> each register's 32 lanes store one
// contiguous 128B row segment of attn. No LDS, no barriers, pure streaming writes.
__global__ __launch_bounds__(256) void attn_store(
    const u16* __restrict__ qh, const u16* __restrict__ kh,
    const float* __restrict__ mask, const float* __restrict__ inv_g,
    float* __restrict__ attn_out)
{
  const int tid = threadIdx.x;
  const int lane = tid & 63, w = tid >> 6;
  const int q_l = lane & 31, hi = lane >> 5;
  const int qb = blockIdx.x, bh = blockIdx.y;
  const int b = bh >> 4;
  const int q0 = qb * 32;

  const u16* Qp = qh + (size_t)bh * S_LEN * DHEAD;
  const u16* Kp = kh + (size_t)bh * S_LEN * DHEAD;

  bf16x8 qf[4];
  {
    const u16* qrow = Qp + (size_t)(q0 + q_l) * DHEAD + hi * 8;
#pragma unroll
    for (int c = 0; c < 4; ++c) qf[c] = *reinterpret_cast<const bf16x8*>(qrow + c * 16);
  }

  float myinv[16];
#pragma unroll
  for (int r = 0; r < 16; ++r)
    myinv[r] = inv_g[(size_t)bh * S_LEN + q0 + (r & 3) + 8 * (r >> 2) + 4 * hi];

  const int k0w = w * 512;
  float mval[16];
#pragma unroll
  for (int t = 0; t < 16; ++t)
    mval[t] = mask[(size_t)b * S_LEN + k0w + t * 32 + q_l] * -1e9f;

  float* base = attn_out + ((size_t)bh * S_LEN + q0 + 4 * hi) * S_LEN + k0w + q_l;

  bf16x8 kc[4], kn[4];
  {
    const u16* kr0 = Kp + (size_t)(k0w + q_l) * DHEAD + hi * 8;
#pragma unroll
    for (int c = 0; c < 4; ++c) kc[c] = *reinterpret_cast<const bf16x8*>(kr0 + c * 16);
  }

#pragma unroll
  for (int t = 0; t < 16; ++t) {
    if (t < 15) {
      const u16* krow = Kp + (size_t)(k0w + (t + 1) * 32 + q_l) * DHEAD + hi * 8;
#pragma unroll
      for (int c = 0; c < 4; ++c) kn[c] = *reinterpret_cast<const bf16x8*>(krow + c * 16);
    }
    f32x16 a0, a1;
#pragma unroll
    for (int r = 0; r < 16; ++r) { a0[r] = 0.f; a1[r] = 0.f; }
    a0 = __builtin_amdgcn_mfma_f32_32x32x16_bf16(qf[0], kc[0], a0, 0, 0, 0);
    a0 = __builtin_amdgcn_mfma_f32_32x32x16_bf16(qf[1], kc[1], a0, 0, 0, 0);
    a1 = __builtin_amdgcn_mfma_f32_32x32x16_bf16(qf[2], kc[2], a1, 0, 0, 0);
    a1 = __builtin_amdgcn_mfma_f32_32x32x16_bf16(qf[3], kc[3], a1, 0, 0, 0);
#pragma unroll
    for (int r = 0; r < 16; ++r) {
      const float pv = __expf(a0[r] + a1[r] + mval[t]) * myinv[r];
      const int rr = (r & 3) + 8 * (r >> 2);
      base[(size_t)rr * S_LEN + t * 32] = pv;
    }
#pragma unroll
    for (int c = 0; c < 4; ++c) kc[c] = kn[c];
  }
}

extern "C" void kernel_launch(void* const* d_in, const int* in_sizes, int n_in,
                              void* d_out, int out_size, void* d_ws, size_t ws_size,
                              hipStream_t stream)
{
  (void)in_sizes; (void)n_in; (void)out_size; (void)ws_size;
  const float* v    = (const float*)d_in[0];
  const float* k    = (const float*)d_in[1];
  const float* q    = (const float*)d_in[2];
  const float* mask = (const float*)d_in[3];
  const float* Wq   = (const float*)d_in[4];
  const float* bq   = (const float*)d_in[5];
  const float* Wk   = (const float*)d_in[6];
  const float* bk   = (const float*)d_in[7];
  const float* Wv   = (const float*)d_in[8];
  const float* bv   = (const float*)d_in[9];
  const float* Wo   = (const float*)d_in[10];
  const float* bo   = (const float*)d_in[11];

  u16* ws16 = (u16*)d_ws;
  u16* xq  = ws16;
  u16* xk  = ws16 + (size_t)1 * NE;
  u16* xv  = ws16 + (size_t)2 * NE;
  u16* qh  = ws16 + (size_t)3 * NE;
  u16* kh  = ws16 + (size_t)4 * NE;
  u16* vh  = ws16 + (size_t)5 * NE;
  u16* wqt = ws16 + (size_t)6 * NE;
  u16* wkt = wqt + WN;
  u16* wvt = wkt + WN;
  u16* wot = wvt + WN;
  float* inv_g = (float*)(wot + WN);   // 32*2048 f32 = 256 KB
  u16* vt  = xq;   // alias: xq dead after gemm_qkv
  u16* ctx = xk;   // alias: xk dead after gemm_qkv

  float* outp  = (float*)d_out;
  float* attnp = outp + (size_t)NE;

  cvt_inputs<<<dim3(1024), dim3(256), 0, stream>>>(q, k, v, xq, xk, xv);
  wtrans<<<dim3(16, 16, 4), dim3(256), 0, stream>>>(Wq, Wk, Wv, Wo, wqt, wkt, wvt, wot);
  gemm_qkv<<<dim3(8, 32, 3), dim3(256), 0, stream>>>(xq, xk, xv, wqt, wkt, wvt,
                                                     bq, bk, bv, qh, kh, vh);
  vtrans<<<dim3(32, 32), dim3(256), 0, stream>>>(vh, vt);
  attn_pv<<<dim3(16, 32), dim3(256), 0, stream>>>(qh, kh, vt, mask, inv_g, ctx);
  attn_store<<<dim3(64, 32), dim3(256), 0, stream>>>(qh, kh, mask, inv_g, attnp);
  gemm_out<<<dim3(8, 32), dim3(256), 0, stream>>>(ctx, wot, bo, outp);
}

// Round 5
// 328.693 us; speedup vs baseline: 1.5728x; 1.0967x over previous
//
#include <hip/hip_runtime.h>
#include <stdint.h>

#define S_LEN 2048
#define DMODEL 1024
#define NHEAD 16
#define DHEAD 64
#define NBATCH 2
#define NE 4194304   // NBATCH*S_LEN*DMODEL
#define WN 1048576   // DMODEL*DMODEL

typedef unsigned short u16;
typedef float f32x16 __attribute__((ext_vector_type(16)));
typedef __bf16 bf16x8 __attribute__((ext_vector_type(8)));

__device__ __forceinline__ u16 f2bf(float x) {
  union { float f; unsigned u; } v; v.f = x;
  unsigned r = v.u + 0x7fffu + ((v.u >> 16) & 1u);
  return (u16)(r >> 16);
}
__device__ __forceinline__ unsigned cvt_pk_bf16(float lo, float hi) {
  unsigned r;
  asm("v_cvt_pk_bf16_f32 %0, %1, %2" : "=v"(r) : "v"(lo), "v"(hi));
  return r;
}
__device__ __forceinline__ void gld_lds16(const void* g, void* l) {
  __builtin_amdgcn_global_load_lds(
      (const __attribute__((address_space(1))) unsigned*)g,
      (__attribute__((address_space(3))) unsigned*)l, 16, 0, 0);
}

// ---------------- convert q,k,v f32 -> bf16 ----------------
__global__ __launch_bounds__(256) void cvt_inputs(
    const float* __restrict__ q, const float* __restrict__ k, const float* __restrict__ v,
    u16* __restrict__ xq, u16* __restrict__ xk, u16* __restrict__ xv)
{
  int i = blockIdx.x * 256 + threadIdx.x;
  const int stride = gridDim.x * 256;
  for (; i < NE / 4; i += stride) {
    float4 a = ((const float4*)q)[i];
    float4 b = ((const float4*)k)[i];
    float4 c = ((const float4*)v)[i];
    ushort4 oa, ob, oc;
    oa.x = f2bf(a.x); oa.y = f2bf(a.y); oa.z = f2bf(a.z); oa.w = f2bf(a.w);
    ob.x = f2bf(b.x); ob.y = f2bf(b.y); ob.z = f2bf(b.z); ob.w = f2bf(b.w);
    oc.x = f2bf(c.x); oc.y = f2bf(c.y); oc.z = f2bf(c.z); oc.w = f2bf(c.w);
    ((ushort4*)xq)[i] = oa;
    ((ushort4*)xk)[i] = ob;
    ((ushort4*)xv)[i] = oc;
  }
}

// ---------------- convert + transpose weights: W[k][n] -> WT[n][k] bf16 ----------------
__global__ __launch_bounds__(256) void wtrans(
    const float* __restrict__ Wq, const float* __restrict__ Wk,
    const float* __restrict__ Wv, const float* __restrict__ Wo,
    u16* __restrict__ oq, u16* __restrict__ ok, u16* __restrict__ ov, u16* __restrict__ oo)
{
  __shared__ u16 t[64][65];
  const float* W; u16* O;
  if (blockIdx.z == 0)      { W = Wq; O = oq; }
  else if (blockIdx.z == 1) { W = Wk; O = ok; }
  else if (blockIdx.z == 2) { W = Wv; O = ov; }
  else                      { W = Wo; O = oo; }
  const int tid = threadIdx.x;
  const int r0 = blockIdx.y * 64, c0 = blockIdx.x * 64;
#pragma unroll
  for (int i = 0; i < 4; ++i) {
    const int row = i * 16 + (tid >> 4);
    const int col = (tid & 15) * 4;
    float4 wv = *(const float4*)(W + (size_t)(r0 + row) * DMODEL + c0 + col);
    t[row][col + 0] = f2bf(wv.x);
    t[row][col + 1] = f2bf(wv.y);
    t[row][col + 2] = f2bf(wv.z);
    t[row][col + 3] = f2bf(wv.w);
  }
  __syncthreads();
#pragma unroll
  for (int i = 0; i < 4; ++i) {
    const int row = i * 16 + (tid >> 4);
    const int col = (tid & 15) * 4;
    ushort4 o;
    o.x = t[col + 0][row]; o.y = t[col + 1][row];
    o.z = t[col + 2][row]; o.w = t[col + 3][row];
    *(ushort4*)(O + (size_t)(c0 + row) * DMODEL + r0 + col) = o;
  }
}

// ---------------- 128x128 bf16 MFMA GEMM, B^T input, global_load_lds staging ----------------
template <int OUTMODE>
__device__ __forceinline__ void gemm_core(
    const u16* __restrict__ A, const u16* __restrict__ Bt,
    const float* __restrict__ bias, void* __restrict__ outp,
    float scale, int m0, int n0)
{
  __shared__ u16 As[128 * 32];
  __shared__ u16 Bs[128 * 32];
  const int tid = threadIdx.x;
  const int lane = tid & 63, w = tid >> 6;
  const int q_l = lane & 31, hi = lane >> 5;
  const int wr = w >> 1, wc = w & 1;

  f32x16 acc[2][2];
#pragma unroll
  for (int a = 0; a < 2; ++a)
#pragma unroll
    for (int b = 0; b < 2; ++b)
#pragma unroll
      for (int r = 0; r < 16; ++r) acc[a][b][r] = 0.f;

  const u16* srcA = A + (size_t)(m0 + (tid >> 2)) * DMODEL + (tid & 3) * 8;
  const u16* srcB = Bt + (size_t)(n0 + (tid >> 2)) * DMODEL + (tid & 3) * 8;
  u16* dstA = As + w * 512;
  u16* dstB = Bs + w * 512;

  for (int kt = 0; kt < DMODEL; kt += 32) {
    gld_lds16(srcA + kt, dstA);
    gld_lds16(srcA + kt + (size_t)64 * DMODEL, dstA + 2048);
    gld_lds16(srcB + kt, dstB);
    gld_lds16(srcB + kt + (size_t)64 * DMODEL, dstB + 2048);
    __syncthreads();
#pragma unroll
    for (int kk = 0; kk < 2; ++kk) {
      bf16x8 af[2], bfv[2];
#pragma unroll
      for (int mb = 0; mb < 2; ++mb)
        af[mb] = *reinterpret_cast<const bf16x8*>(&As[(wr * 64 + mb * 32 + q_l) * 32 + kk * 16 + hi * 8]);
#pragma unroll
      for (int nb = 0; nb < 2; ++nb)
        bfv[nb] = *reinterpret_cast<const bf16x8*>(&Bs[(wc * 64 + nb * 32 + q_l) * 32 + kk * 16 + hi * 8]);
#pragma unroll
      for (int mb = 0; mb < 2; ++mb)
#pragma unroll
        for (int nb = 0; nb < 2; ++nb)
          acc[mb][nb] = __builtin_amdgcn_mfma_f32_32x32x16_bf16(af[mb], bfv[nb], acc[mb][nb], 0, 0, 0);
    }
    __syncthreads();
  }

#pragma unroll
  for (int mb = 0; mb < 2; ++mb) {
#pragma unroll
    for (int nb = 0; nb < 2; ++nb) {
      const int n = n0 + wc * 64 + nb * 32 + q_l;
      const float bn = bias[n];
#pragma unroll
      for (int r = 0; r < 16; ++r) {
        const int m = m0 + wr * 64 + mb * 32 + (r & 3) + 8 * (r >> 2) + 4 * hi;
        const float val = (acc[mb][nb][r] + bn) * scale;
        if (OUTMODE == 0) {
          const int bb = m >> 11, s = m & 2047, hh = n >> 6, d = n & 63;
          ((u16*)outp)[(((size_t)(bb * NHEAD + hh)) * S_LEN + s) * DHEAD + d] = f2bf(val);
        } else {
          ((float*)outp)[(size_t)m * DMODEL + n] = val;
        }
      }
    }
  }
}

__global__ __launch_bounds__(256) void gemm_qkv(
    const u16* __restrict__ xq, const u16* __restrict__ xk, const u16* __restrict__ xv,
    const u16* __restrict__ wqt, const u16* __restrict__ wkt, const u16* __restrict__ wvt,
    const float* __restrict__ bq, const float* __restrict__ bk, const float* __restrict__ bv,
    u16* __restrict__ qh, u16* __restrict__ kh, u16* __restrict__ vh)
{
  const u16 *A, *Bt; const float* bias; u16* O; float scale;
  if (blockIdx.z == 0)      { A = xq; Bt = wqt; bias = bq; O = qh; scale = 0.125f; }
  else if (blockIdx.z == 1) { A = xk; Bt = wkt; bias = bk; O = kh; scale = 1.f; }
  else                      { A = xv; Bt = wvt; bias = bv; O = vh; scale = 1.f; }
  gemm_core<0>(A, Bt, bias, O, scale, blockIdx.y * 128, blockIdx.x * 128);
}

// ---------------- transpose Vh[bh][s][d] -> Vt[bh][d][s] ----------------
__global__ __launch_bounds__(256) void vtrans(const u16* __restrict__ vh, u16* __restrict__ vt)
{
  __shared__ u16 t[64][72];
  const int tid = threadIdx.x;
  const int bh = blockIdx.y;
  const int s0 = blockIdx.x * 64;
  const u16* src = vh + (size_t)bh * S_LEN * DHEAD;
  u16* dst = vt + (size_t)bh * DHEAD * S_LEN;
#pragma unroll
  for (int i = 0; i < 2; ++i) {
    const int row = i * 32 + (tid >> 3);
    const int c8 = (tid & 7) * 8;
    *(uint4*)&t[row][c8] = *(const uint4*)(src + (size_t)(s0 + row) * DHEAD + c8);
  }
  __syncthreads();
#pragma unroll
  for (int i = 0; i < 2; ++i) {
    const int d = i * 32 + (tid >> 3);
    const int c8 = (tid & 7) * 8;
    unsigned p0 = (unsigned)t[c8 + 0][d] | ((unsigned)t[c8 + 1][d] << 16);
    unsigned p1 = (unsigned)t[c8 + 2][d] | ((unsigned)t[c8 + 3][d] << 16);
    unsigned p2 = (unsigned)t[c8 + 4][d] | ((unsigned)t[c8 + 5][d] << 16);
    unsigned p3 = (unsigned)t[c8 + 6][d] | ((unsigned)t[c8 + 7][d] << 16);
    uint4 o; o.x = p0; o.y = p1; o.z = p2; o.w = p3;
    *(uint4*)(dst + (size_t)d * S_LEN + s0 + c8) = o;
  }
}

// ---------------- attn kernel A v4: 1-wave blocks, no LDS, XCD-swizzled ----------------
// grid 2048 x 64 threads. Block id -> (qb, bh) with id%8 == bh%8 so all q-blocks of a
// head land on one XCD (K/V L2-resident). Wave owns 32 q rows, sweeps 64 k-tiles with
// K AND V prefetched one tile ahead. Swapped QK (mfma(K,Q)); denominator in-lane.
__global__ __launch_bounds__(64) void attn_pv(
    const u16* __restrict__ qh, const u16* __restrict__ kh,
    const u16* __restrict__ vt, const float* __restrict__ mask,
    float* __restrict__ inv_g, u16* __restrict__ ctx_out)
{
  const int lane = threadIdx.x;
  const int q_l = lane & 31, hi = lane >> 5;
  const int id = blockIdx.x;
  const int bh = (id & 7) | (((id >> 3) & 3) << 3);
  const int qb = id >> 5;
  const int b = bh >> 4, h = bh & 15;
  const int q0 = qb * 32;

  const u16* Qp = qh + (size_t)bh * S_LEN * DHEAD;
  const u16* Kp = kh + (size_t)bh * S_LEN * DHEAD;
  const u16* Vp = vt + (size_t)bh * DHEAD * S_LEN;
  const float* mrow = mask + (size_t)b * S_LEN;

  bf16x8 qf[4];
  {
    const u16* qrow = Qp + (size_t)(q0 + q_l) * DHEAD + hi * 8;
#pragma unroll
    for (int c = 0; c < 4; ++c) qf[c] = *reinterpret_cast<const bf16x8*>(qrow + c * 16);
  }

  float rsum = 0.f;
  f32x16 cacc[2];
#pragma unroll
  for (int db = 0; db < 2; ++db)
#pragma unroll
    for (int r = 0; r < 16; ++r) cacc[db][r] = 0.f;

  bf16x8 kc[4], kn[4], vc[2][2], vn[2][2];
  {
    const u16* kr0 = Kp + (size_t)q_l * DHEAD + hi * 8;
#pragma unroll
    for (int c = 0; c < 4; ++c) kc[c] = *reinterpret_cast<const bf16x8*>(kr0 + c * 16);
#pragma unroll
    for (int s2 = 0; s2 < 2; ++s2)
#pragma unroll
      for (int db = 0; db < 2; ++db)
        vc[s2][db] = *reinterpret_cast<const bf16x8*>(
            Vp + (size_t)(db * 32 + q_l) * S_LEN + s2 * 16 + hi * 8);
  }

#pragma unroll 2
  for (int t = 0; t < 64; ++t) {
    const int k0 = t * 32;
    // prefetch next tile's K and V (independent of all compute below)
    if (t < 63) {
      const u16* krow = Kp + (size_t)(k0 + 32 + q_l) * DHEAD + hi * 8;
#pragma unroll
      for (int c = 0; c < 4; ++c) kn[c] = *reinterpret_cast<const bf16x8*>(krow + c * 16);
#pragma unroll
      for (int s2 = 0; s2 < 2; ++s2)
#pragma unroll
        for (int db = 0; db < 2; ++db)
          vn[s2][db] = *reinterpret_cast<const bf16x8*>(
              Vp + (size_t)(db * 32 + q_l) * S_LEN + k0 + 32 + s2 * 16 + hi * 8);
    }
    // QK: two independent 2-deep MFMA chains
    f32x16 a0, a1;
#pragma unroll
    for (int r = 0; r < 16; ++r) { a0[r] = 0.f; a1[r] = 0.f; }
    a0 = __builtin_amdgcn_mfma_f32_32x32x16_bf16(kc[0], qf[0], a0, 0, 0, 0);
    a0 = __builtin_amdgcn_mfma_f32_32x32x16_bf16(kc[1], qf[1], a0, 0, 0, 0);
    a1 = __builtin_amdgcn_mfma_f32_32x32x16_bf16(kc[2], qf[2], a1, 0, 0, 0);
    a1 = __builtin_amdgcn_mfma_f32_32x32x16_bf16(kc[3], qf[3], a1, 0, 0, 0);

    float p[16];
#pragma unroll
    for (int g = 0; g < 4; ++g) {
      // rows for r=4g+j are k-local kl = j + 8g + 4hi -> one float4 mask load (L1-hot)
      const float4 mk = *(const float4*)&mrow[k0 + 8 * g + 4 * hi];
      p[4 * g + 0] = __expf(a0[4 * g + 0] + a1[4 * g + 0] + mk.x * -1e9f);
      p[4 * g + 1] = __expf(a0[4 * g + 1] + a1[4 * g + 1] + mk.y * -1e9f);
      p[4 * g + 2] = __expf(a0[4 * g + 2] + a1[4 * g + 2] + mk.z * -1e9f);
      p[4 * g + 3] = __expf(a0[4 * g + 3] + a1[4 * g + 3] + mk.w * -1e9f);
      rsum += (p[4 * g + 0] + p[4 * g + 1]) + (p[4 * g + 2] + p[4 * g + 3]);
    }
    unsigned pk[8];
#pragma unroll
    for (int g = 0; g < 4; ++g) {
      pk[2 * g + 0] = cvt_pk_bf16(p[4 * g + 0], p[4 * g + 1]);
      pk[2 * g + 1] = cvt_pk_bf16(p[4 * g + 2], p[4 * g + 3]);
    }
#pragma unroll
    for (int s2 = 0; s2 < 2; ++s2) {
      unsigned a0u = pk[4 * s2 + 0], b0u = pk[4 * s2 + 2];
      unsigned a1u = pk[4 * s2 + 1], b1u = pk[4 * s2 + 3];
      asm volatile("v_permlane32_swap_b32 %0, %1" : "+v"(a0u), "+v"(b0u));
      asm volatile("v_permlane32_swap_b32 %0, %1" : "+v"(a1u), "+v"(b1u));
      uint4 frw; frw.x = a0u; frw.y = a1u; frw.z = b0u; frw.w = b1u;
      bf16x8 pa = __builtin_bit_cast(bf16x8, frw);
#pragma unroll
      for (int db = 0; db < 2; ++db)
        cacc[db] = __builtin_amdgcn_mfma_f32_32x32x16_bf16(pa, vc[s2][db], cacc[db], 0, 0, 0);
    }
#pragma unroll
    for (int c = 0; c < 4; ++c) kc[c] = kn[c];
#pragma unroll
    for (int s2 = 0; s2 < 2; ++s2)
#pragma unroll
      for (int db = 0; db < 2; ++db) vc[s2][db] = vn[s2][db];
  }

  rsum += __shfl_xor(rsum, 32, 64);
  const float inv = 1.0f / rsum;            // lane i (i<32) holds q0+i
  if (lane < 32) inv_g[(size_t)bh * S_LEN + q0 + lane] = inv;

  float sc[16];
#pragma unroll
  for (int r = 0; r < 16; ++r)
    sc[r] = __shfl(inv, (r & 3) + 8 * (r >> 2) + 4 * hi, 64);
#pragma unroll
  for (int db = 0; db < 2; ++db)
#pragma unroll
    for (int r = 0; r < 16; ++r) {
      const int qq = (r & 3) + 8 * (r >> 2) + 4 * hi;
      ctx_out[((size_t)(b * S_LEN + q0 + qq)) * DMODEL + h * DHEAD + db * 32 + q_l] =
          f2bf(cacc[db][r] * sc[r]);
    }
}

// ---------------- fused tail: gemm_out (blocks 0..255) + attn_store (blocks 256..2303) ----
// Both depend only on attn_pv outputs; fusing lets the ~15us GEMM hide under the
// write-bound attn store. attn_store: unswapped mfma(Q,K) -> C col = k index -> each
// register's 32 lanes store one contiguous 128B row segment. XCD-swizzled bh decode.
__global__ __launch_bounds__(256) void tail_fused(
    const u16* __restrict__ ctx, const u16* __restrict__ wot, const float* __restrict__ bo,
    float* __restrict__ out,
    const u16* __restrict__ qh, const u16* __restrict__ kh,
    const float* __restrict__ mask, const float* __restrict__ inv_g,
    float* __restrict__ attn_out)
{
  if (blockIdx.x < 256) {
    const int gid = blockIdx.x;
    gemm_core<1>(ctx, wot, bo, out, 1.f, (gid >> 3) * 128, (gid & 7) * 128);
    return;
  }
  const int id = blockIdx.x - 256;          // 256 = 0 mod 8: XCD phase preserved
  const int tid = threadIdx.x;
  const int lane = tid & 63, w = tid >> 6;
  const int q_l = lane & 31, hi = lane >> 5;
  const int bh = (id & 7) | (((id >> 3) & 3) << 3);
  const int qb = id >> 5;
  const int b = bh >> 4;
  const int q0 = qb * 32;

  const u16* Qp = qh + (size_t)bh * S_LEN * DHEAD;
  const u16* Kp = kh + (size_t)bh * S_LEN * DHEAD;

  bf16x8 qf[4];
  {
    const u16* qrow = Qp + (size_t)(q0 + q_l) * DHEAD + hi * 8;
#pragma unroll
    for (int c = 0; c < 4; ++c) qf[c] = *reinterpret_cast<const bf16x8*>(qrow + c * 16);
  }

  float myinv[16];
#pragma unroll
  for (int r = 0; r < 16; ++r)
    myinv[r] = inv_g[(size_t)bh * S_LEN + q0 + (r & 3) + 8 * (r >> 2) + 4 * hi];

  const int k0w = w * 512;
  float mval[16];
#pragma unroll
  for (int t = 0; t < 16; ++t)
    mval[t] = mask[(size_t)b * S_LEN + k0w + t * 32 + q_l] * -1e9f;

  float* base = attn_out + ((size_t)bh * S_LEN + q0 + 4 * hi) * S_LEN + k0w + q_l;

  bf16x8 kc[4], kn[4];
  {
    const u16* kr0 = Kp + (size_t)(k0w + q_l) * DHEAD + hi * 8;
#pragma unroll
    for (int c = 0; c < 4; ++c) kc[c] = *reinterpret_cast<const bf16x8*>(kr0 + c * 16);
  }

#pragma unroll
  for (int t = 0; t < 16; ++t) {
    if (t < 15) {
      const u16* krow = Kp + (size_t)(k0w + (t + 1) * 32 + q_l) * DHEAD + hi * 8;
#pragma unroll
      for (int c = 0; c < 4; ++c) kn[c] = *reinterpret_cast<const bf16x8*>(krow + c * 16);
    }
    f32x16 a0, a1;
#pragma unroll
    for (int r = 0; r < 16; ++r) { a0[r] = 0.f; a1[r] = 0.f; }
    a0 = __builtin_amdgcn_mfma_f32_32x32x16_bf16(qf[0], kc[0], a0, 0, 0, 0);
    a0 = __builtin_amdgcn_mfma_f32_32x32x16_bf16(qf[1], kc[1], a0, 0, 0, 0);
    a1 = __builtin_amdgcn_mfma_f32_32x32x16_bf16(qf[2], kc[2], a1, 0, 0, 0);
    a1 = __builtin_amdgcn_mfma_f32_32x32x16_bf16(qf[3], kc[3], a1, 0, 0, 0);
#pragma unroll
    for (int r = 0; r < 16; ++r) {
      const float pv = __expf(a0[r] + a1[r] + mval[t]) * myinv[r];
      const int rr = (r & 3) + 8 * (r >> 2);
      base[(size_t)rr * S_LEN + t * 32] = pv;
    }
#pragma unroll
    for (int c = 0; c < 4; ++c) kc[c] = kn[c];
  }
}

extern "C" void kernel_launch(void* const* d_in, const int* in_sizes, int n_in,
                              void* d_out, int out_size, void* d_ws, size_t ws_size,
                              hipStream_t stream)
{
  (void)in_sizes; (void)n_in; (void)out_size; (void)ws_size;
  const float* v    = (const float*)d_in[0];
  const float* k    = (const float*)d_in[1];
  const float* q    = (const float*)d_in[2];
  const float* mask = (const float*)d_in[3];
  const float* Wq   = (const float*)d_in[4];
  const float* bq   = (const float*)d_in[5];
  const float* Wk   = (const float*)d_in[6];
  const float* bk   = (const float*)d_in[7];
  const float* Wv   = (const float*)d_in[8];
  const float* bv   = (const float*)d_in[9];
  const float* Wo   = (const float*)d_in[10];
  const float* bo   = (const float*)d_in[11];

  u16* ws16 = (u16*)d_ws;
  u16* xq  = ws16;
  u16* xk  = ws16 + (size_t)1 * NE;
  u16* xv  = ws16 + (size_t)2 * NE;
  u16* qh  = ws16 + (size_t)3 * NE;
  u16* kh  = ws16 + (size_t)4 * NE;
  u16* vh  = ws16 + (size_t)5 * NE;
  u16* wqt = ws16 + (size_t)6 * NE;
  u16* wkt = wqt + WN;
  u16* wvt = wkt + WN;
  u16* wot = wvt + WN;
  float* inv_g = (float*)(wot + WN);   // 32*2048 f32 = 256 KB
  u16* vt  = xq;   // alias: xq dead after gemm_qkv
  u16* ctx = xk;   // alias: xk dead after gemm_qkv

  float* outp  = (float*)d_out;
  float* attnp = outp + (size_t)NE;

  cvt_inputs<<<dim3(1024), dim3(256), 0, stream>>>(q, k, v, xq, xk, xv);
  wtrans<<<dim3(16, 16, 4), dim3(256), 0, stream>>>(Wq, Wk, Wv, Wo, wqt, wkt, wvt, wot);
  gemm_qkv<<<dim3(8, 32, 3), dim3(256), 0, stream>>>(xq, xk, xv, wqt, wkt, wvt,
                                                     bq, bk, bv, qh, kh, vh);
  vtrans<<<dim3(32, 32), dim3(256), 0, stream>>>(vh, vt);
  attn_pv<<<dim3(2048), dim3(64), 0, stream>>>(qh, kh, vt, mask, inv_g, ctx);
  tail_fused<<<dim3(2304), dim3(256), 0, stream>>>(ctx, wot, bo, outp,
                                                   qh, kh, mask, inv_g, attnp);
}

// Round 7
// 314.083 us; speedup vs baseline: 1.6460x; 1.0465x over previous
//
#include <hip/hip_runtime.h>
#include <stdint.h>

#define S_LEN 2048
#define DMODEL 1024
#define NHEAD 16
#define DHEAD 64
#define NBATCH 2
#define NE 4194304   // NBATCH*S_LEN*DMODEL
#define WN 1048576   // DMODEL*DMODEL

typedef unsigned short u16;
typedef float f32x16 __attribute__((ext_vector_type(16)));
typedef __bf16 bf16x8 __attribute__((ext_vector_type(8)));

__device__ __forceinline__ u16 f2bf(float x) {
  union { float f; unsigned u; } v; v.f = x;
  unsigned r = v.u + 0x7fffu + ((v.u >> 16) & 1u);
  return (u16)(r >> 16);
}
__device__ __forceinline__ unsigned cvt_pk_bf16(float lo, float hi) {
  unsigned r;
  asm("v_cvt_pk_bf16_f32 %0, %1, %2" : "=v"(r) : "v"(lo), "v"(hi));
  return r;
}
__device__ __forceinline__ void gld_lds16(const void* g, void* l) {
  __builtin_amdgcn_global_load_lds(
      (const __attribute__((address_space(1))) unsigned*)g,
      (__attribute__((address_space(3))) unsigned*)l, 16, 0, 0);
}

// ---------------- convert q,k,v f32 -> bf16 ----------------
__global__ __launch_bounds__(256) void cvt_inputs(
    const float* __restrict__ q, const float* __restrict__ k, const float* __restrict__ v,
    u16* __restrict__ xq, u16* __restrict__ xk, u16* __restrict__ xv)
{
  int i = blockIdx.x * 256 + threadIdx.x;
  const int stride = gridDim.x * 256;
  for (; i < NE / 4; i += stride) {
    float4 a = ((const float4*)q)[i];
    float4 b = ((const float4*)k)[i];
    float4 c = ((const float4*)v)[i];
    ushort4 oa, ob, oc;
    oa.x = f2bf(a.x); oa.y = f2bf(a.y); oa.z = f2bf(a.z); oa.w = f2bf(a.w);
    ob.x = f2bf(b.x); ob.y = f2bf(b.y); ob.z = f2bf(b.z); ob.w = f2bf(b.w);
    oc.x = f2bf(c.x); oc.y = f2bf(c.y); oc.z = f2bf(c.z); oc.w = f2bf(c.w);
    ((ushort4*)xq)[i] = oa;
    ((ushort4*)xk)[i] = ob;
    ((ushort4*)xv)[i] = oc;
  }
}

// ---------------- convert + transpose weights: W[k][n] -> WT[n][k] bf16 ----------------
__global__ __launch_bounds__(256) void wtrans(
    const float* __restrict__ Wq, const float* __restrict__ Wk,
    const float* __restrict__ Wv, const float* __restrict__ Wo,
    u16* __restrict__ oq, u16* __restrict__ ok, u16* __restrict__ ov, u16* __restrict__ oo)
{
  __shared__ u16 t[64][65];
  const float* W; u16* O;
  if (blockIdx.z == 0)      { W = Wq; O = oq; }
  else if (blockIdx.z == 1) { W = Wk; O = ok; }
  else if (blockIdx.z == 2) { W = Wv; O = ov; }
  else                      { W = Wo; O = oo; }
  const int tid = threadIdx.x;
  const int r0 = blockIdx.y * 64, c0 = blockIdx.x * 64;
#pragma unroll
  for (int i = 0; i < 4; ++i) {
    const int row = i * 16 + (tid >> 4);
    const int col = (tid & 15) * 4;
    float4 wv = *(const float4*)(W + (size_t)(r0 + row) * DMODEL + c0 + col);
    t[row][col + 0] = f2bf(wv.x);
    t[row][col + 1] = f2bf(wv.y);
    t[row][col + 2] = f2bf(wv.z);
    t[row][col + 3] = f2bf(wv.w);
  }
  __syncthreads();
#pragma unroll
  for (int i = 0; i < 4; ++i) {
    const int row = i * 16 + (tid >> 4);
    const int col = (tid & 15) * 4;
    ushort4 o;
    o.x = t[col + 0][row]; o.y = t[col + 1][row];
    o.z = t[col + 2][row]; o.w = t[col + 3][row];
    *(ushort4*)(O + (size_t)(c0 + row) * DMODEL + r0 + col) = o;
  }
}

// ---------------- 128x128 bf16 MFMA GEMM, B^T input, global_load_lds staging ----------------
template <int OUTMODE>
__device__ __forceinline__ void gemm_core(
    const u16* __restrict__ A, const u16* __restrict__ Bt,
    const float* __restrict__ bias, void* __restrict__ outp,
    float scale, int m0, int n0)
{
  __shared__ u16 As[128 * 32];
  __shared__ u16 Bs[128 * 32];
  const int tid = threadIdx.x;
  const int lane = tid & 63, w = tid >> 6;
  const int q_l = lane & 31, hi = lane >> 5;
  const int wr = w >> 1, wc = w & 1;

  f32x16 acc[2][2];
#pragma unroll
  for (int a = 0; a < 2; ++a)
#pragma unroll
    for (int b = 0; b < 2; ++b)
#pragma unroll
      for (int r = 0; r < 16; ++r) acc[a][b][r] = 0.f;

  const u16* srcA = A + (size_t)(m0 + (tid >> 2)) * DMODEL + (tid & 3) * 8;
  const u16* srcB = Bt + (size_t)(n0 + (tid >> 2)) * DMODEL + (tid & 3) * 8;
  u16* dstA = As + w * 512;
  u16* dstB = Bs + w * 512;

  for (int kt = 0; kt < DMODEL; kt += 32) {
    gld_lds16(srcA + kt, dstA);
    gld_lds16(srcA + kt + (size_t)64 * DMODEL, dstA + 2048);
    gld_lds16(srcB + kt, dstB);
    gld_lds16(srcB + kt + (size_t)64 * DMODEL, dstB + 2048);
    __syncthreads();
#pragma unroll
    for (int kk = 0; kk < 2; ++kk) {
      bf16x8 af[2], bfv[2];
#pragma unroll
      for (int mb = 0; mb < 2; ++mb)
        af[mb] = *reinterpret_cast<const bf16x8*>(&As[(wr * 64 + mb * 32 + q_l) * 32 + kk * 16 + hi * 8]);
#pragma unroll
      for (int nb = 0; nb < 2; ++nb)
        bfv[nb] = *reinterpret_cast<const bf16x8*>(&Bs[(wc * 64 + nb * 32 + q_l) * 32 + kk * 16 + hi * 8]);
#pragma unroll
      for (int mb = 0; mb < 2; ++mb)
#pragma unroll
        for (int nb = 0; nb < 2; ++nb)
          acc[mb][nb] = __builtin_amdgcn_mfma_f32_32x32x16_bf16(af[mb], bfv[nb], acc[mb][nb], 0, 0, 0);
    }
    __syncthreads();
  }

#pragma unroll
  for (int mb = 0; mb < 2; ++mb) {
#pragma unroll
    for (int nb = 0; nb < 2; ++nb) {
      const int n = n0 + wc * 64 + nb * 32 + q_l;
      const float bn = bias[n];
#pragma unroll
      for (int r = 0; r < 16; ++r) {
        const int m = m0 + wr * 64 + mb * 32 + (r & 3) + 8 * (r >> 2) + 4 * hi;
        const float val = (acc[mb][nb][r] + bn) * scale;
        if (OUTMODE == 0) {
          const int bb = m >> 11, s = m & 2047, hh = n >> 6, d = n & 63;
          ((u16*)outp)[(((size_t)(bb * NHEAD + hh)) * S_LEN + s) * DHEAD + d] = f2bf(val);
        } else {
          ((float*)outp)[(size_t)m * DMODEL + n] = val;
        }
      }
    }
  }
}

__global__ __launch_bounds__(256) void gemm_qkv(
    const u16* __restrict__ xq, const u16* __restrict__ xk, const u16* __restrict__ xv,
    const u16* __restrict__ wqt, const u16* __restrict__ wkt, const u16* __restrict__ wvt,
    const float* __restrict__ bq, const float* __restrict__ bk, const float* __restrict__ bv,
    u16* __restrict__ qh, u16* __restrict__ kh, u16* __restrict__ vh)
{
  const u16 *A, *Bt; const float* bias; u16* O; float scale;
  if (blockIdx.z == 0)      { A = xq; Bt = wqt; bias = bq; O = qh; scale = 0.125f; }
  else if (blockIdx.z == 1) { A = xk; Bt = wkt; bias = bk; O = kh; scale = 1.f; }
  else                      { A = xv; Bt = wvt; bias = bv; O = vh; scale = 1.f; }
  gemm_core<0>(A, Bt, bias, O, scale, blockIdx.y * 128, blockIdx.x * 128);
}

// ---------------- transpose Vh[bh][s][d] -> Vt[bh][d][s], producer-XCD aligned ----------------
// 1D grid 1024: bits 0-2 -> h>>1 (= producer XCD of head h), bit 3 -> h&1, bit 4 -> b,
// bits 5-9 -> s-block. Bijective over (h, b, s0).
__global__ __launch_bounds__(256) void vtrans(const u16* __restrict__ vh, u16* __restrict__ vt)
{
  __shared__ u16 t[64][72];
  const int tid = threadIdx.x;
  const int id = blockIdx.x;
  const int h = ((id & 7) << 1) | ((id >> 3) & 1);
  const int b = (id >> 4) & 1;
  const int bh = b * 16 + h;
  const int s0 = (id >> 5) * 64;
  const u16* src = vh + (size_t)bh * S_LEN * DHEAD;
  u16* dst = vt + (size_t)bh * DHEAD * S_LEN;
#pragma unroll
  for (int i = 0; i < 2; ++i) {
    const int row = i * 32 + (tid >> 3);
    const int c8 = (tid & 7) * 8;
    *(uint4*)&t[row][c8] = *(const uint4*)(src + (size_t)(s0 + row) * DHEAD + c8);
  }
  __syncthreads();
#pragma unroll
  for (int i = 0; i < 2; ++i) {
    const int d = i * 32 + (tid >> 3);
    const int c8 = (tid & 7) * 8;
    unsigned p0 = (unsigned)t[c8 + 0][d] | ((unsigned)t[c8 + 1][d] << 16);
    unsigned p1 = (unsigned)t[c8 + 2][d] | ((unsigned)t[c8 + 3][d] << 16);
    unsigned p2 = (unsigned)t[c8 + 4][d] | ((unsigned)t[c8 + 5][d] << 16);
    unsigned p3 = (unsigned)t[c8 + 6][d] | ((unsigned)t[c8 + 7][d] << 16);
    uint4 o; o.x = p0; o.y = p1; o.z = p2; o.w = p3;
    *(uint4*)(dst + (size_t)d * S_LEN + s0 + c8) = o;
  }
}

// ---------------- attn kernel A (R5 body): 1-wave blocks, producer-XCD aligned decode ----
// grid 2048 x 64 threads. h = ((id&7)<<1)|((id>>3)&1) -> reader lands on XCD h>>1, the
// same XCD whose gemm_qkv block produced heads {2(id&7), 2(id&7)+1}. K/V L2-resident.
__global__ __launch_bounds__(64) void attn_pv(
    const u16* __restrict__ qh, const u16* __restrict__ kh,
    const u16* __restrict__ vt, const float* __restrict__ mask,
    float* __restrict__ inv_g, u16* __restrict__ ctx_out)
{
  const int lane = threadIdx.x;
  const int q_l = lane & 31, hi = lane >> 5;
  const int id = blockIdx.x;
  const int h = ((id & 7) << 1) | ((id >> 3) & 1);
  const int b = (id >> 4) & 1;
  const int bh = b * 16 + h;
  const int qb = id >> 5;
  const int q0 = qb * 32;

  const u16* Qp = qh + (size_t)bh * S_LEN * DHEAD;
  const u16* Kp = kh + (size_t)bh * S_LEN * DHEAD;
  const u16* Vp = vt + (size_t)bh * DHEAD * S_LEN;
  const float* mrow = mask + (size_t)b * S_LEN;

  bf16x8 qf[4];
  {
    const u16* qrow = Qp + (size_t)(q0 + q_l) * DHEAD + hi * 8;
#pragma unroll
    for (int c = 0; c < 4; ++c) qf[c] = *reinterpret_cast<const bf16x8*>(qrow + c * 16);
  }

  float rsum = 0.f;
  f32x16 cacc[2];
#pragma unroll
  for (int db = 0; db < 2; ++db)
#pragma unroll
    for (int r = 0; r < 16; ++r) cacc[db][r] = 0.f;

  bf16x8 kc[4], kn[4], vc[2][2], vn[2][2];
  {
    const u16* kr0 = Kp + (size_t)q_l * DHEAD + hi * 8;
#pragma unroll
    for (int c = 0; c < 4; ++c) kc[c] = *reinterpret_cast<const bf16x8*>(kr0 + c * 16);
#pragma unroll
    for (int s2 = 0; s2 < 2; ++s2)
#pragma unroll
      for (int db = 0; db < 2; ++db)
        vc[s2][db] = *reinterpret_cast<const bf16x8*>(
            Vp + (size_t)(db * 32 + q_l) * S_LEN + s2 * 16 + hi * 8);
  }

#pragma unroll 2
  for (int t = 0; t < 64; ++t) {
    const int k0 = t * 32;
    // prefetch next tile's K and V (independent of all compute below)
    if (t < 63) {
      const u16* krow = Kp + (size_t)(k0 + 32 + q_l) * DHEAD + hi * 8;
#pragma unroll
      for (int c = 0; c < 4; ++c) kn[c] = *reinterpret_cast<const bf16x8*>(krow + c * 16);
#pragma unroll
      for (int s2 = 0; s2 < 2; ++s2)
#pragma unroll
        for (int db = 0; db < 2; ++db)
          vn[s2][db] = *reinterpret_cast<const bf16x8*>(
              Vp + (size_t)(db * 32 + q_l) * S_LEN + k0 + 32 + s2 * 16 + hi * 8);
    }
    // QK: two independent 2-deep MFMA chains
    f32x16 a0, a1;
#pragma unroll
    for (int r = 0; r < 16; ++r) { a0[r] = 0.f; a1[r] = 0.f; }
    a0 = __builtin_amdgcn_mfma_f32_32x32x16_bf16(kc[0], qf[0], a0, 0, 0, 0);
    a0 = __builtin_amdgcn_mfma_f32_32x32x16_bf16(kc[1], qf[1], a0, 0, 0, 0);
    a1 = __builtin_amdgcn_mfma_f32_32x32x16_bf16(kc[2], qf[2], a1, 0, 0, 0);
    a1 = __builtin_amdgcn_mfma_f32_32x32x16_bf16(kc[3], qf[3], a1, 0, 0, 0);

    float p[16];
#pragma unroll
    for (int g = 0; g < 4; ++g) {
      // rows for r=4g+j are k-local kl = j + 8g + 4hi -> one float4 mask load (L1-hot)
      const float4 mk = *(const float4*)&mrow[k0 + 8 * g + 4 * hi];
      p[4 * g + 0] = __expf(a0[4 * g + 0] + a1[4 * g + 0] + mk.x * -1e9f);
      p[4 * g + 1] = __expf(a0[4 * g + 1] + a1[4 * g + 1] + mk.y * -1e9f);
      p[4 * g + 2] = __expf(a0[4 * g + 2] + a1[4 * g + 2] + mk.z * -1e9f);
      p[4 * g + 3] = __expf(a0[4 * g + 3] + a1[4 * g + 3] + mk.w * -1e9f);
      rsum += (p[4 * g + 0] + p[4 * g + 1]) + (p[4 * g + 2] + p[4 * g + 3]);
    }
    unsigned pk[8];
#pragma unroll
    for (int g = 0; g < 4; ++g) {
      pk[2 * g + 0] = cvt_pk_bf16(p[4 * g + 0], p[4 * g + 1]);
      pk[2 * g + 1] = cvt_pk_bf16(p[4 * g + 2], p[4 * g + 3]);
    }
#pragma unroll
    for (int s2 = 0; s2 < 2; ++s2) {
      unsigned a0u = pk[4 * s2 + 0], b0u = pk[4 * s2 + 2];
      unsigned a1u = pk[4 * s2 + 1], b1u = pk[4 * s2 + 3];
      asm volatile("v_permlane32_swap_b32 %0, %1" : "+v"(a0u), "+v"(b0u));
      asm volatile("v_permlane32_swap_b32 %0, %1" : "+v"(a1u), "+v"(b1u));
      uint4 frw; frw.x = a0u; frw.y = a1u; frw.z = b0u; frw.w = b1u;
      bf16x8 pa = __builtin_bit_cast(bf16x8, frw);
#pragma unroll
      for (int db = 0; db < 2; ++db)
        cacc[db] = __builtin_amdgcn_mfma_f32_32x32x16_bf16(pa, vc[s2][db], cacc[db], 0, 0, 0);
    }
#pragma unroll
    for (int c = 0; c < 4; ++c) kc[c] = kn[c];
#pragma unroll
    for (int s2 = 0; s2 < 2; ++s2)
#pragma unroll
      for (int db = 0; db < 2; ++db) vc[s2][db] = vn[s2][db];
  }

  rsum += __shfl_xor(rsum, 32, 64);
  const float inv = 1.0f / rsum;            // lane i (i<32) holds q0+i
  if (lane < 32) inv_g[(size_t)bh * S_LEN + q0 + lane] = inv;

  float sc[16];
#pragma unroll
  for (int r = 0; r < 16; ++r)
    sc[r] = __shfl(inv, (r & 3) + 8 * (r >> 2) + 4 * hi, 64);
#pragma unroll
  for (int db = 0; db < 2; ++db)
#pragma unroll
    for (int r = 0; r < 16; ++r) {
      const int qq = (r & 3) + 8 * (r >> 2) + 4 * hi;
      ctx_out[((size_t)(b * S_LEN + q0 + qq)) * DMODEL + h * DHEAD + db * 32 + q_l] =
          f2bf(cacc[db][r] * sc[r]);
    }
}

// ---------------- fused tail: gemm_out (blocks 0..255) + attn_store (blocks 256..2303) ----
// attn_store (R5 body): unswapped mfma(Q,K) -> C col = k index -> contiguous 128B row
// segments. Producer-XCD-aligned decode; attn writes are NONTEMPORAL (never re-read,
// keeps K/V L2-resident).
__global__ __launch_bounds__(256) void tail_fused(
    const u16* __restrict__ ctx, const u16* __restrict__ wot, const float* __restrict__ bo,
    float* __restrict__ out,
    const u16* __restrict__ qh, const u16* __restrict__ kh,
    const float* __restrict__ mask, const float* __restrict__ inv_g,
    float* __restrict__ attn_out)
{
  if (blockIdx.x < 256) {
    const int gid = blockIdx.x;
    gemm_core<1>(ctx, wot, bo, out, 1.f, (gid >> 3) * 128, (gid & 7) * 128);
    return;
  }
  const int id = blockIdx.x - 256;          // 256 = 0 mod 8: XCD phase preserved
  const int tid = threadIdx.x;
  const int lane = tid & 63, w = tid >> 6;
  const int q_l = lane & 31, hi = lane >> 5;
  const int h = ((id & 7) << 1) | ((id >> 3) & 1);
  const int b = (id >> 4) & 1;
  const int bh = b * 16 + h;
  const int qb = id >> 5;
  const int q0 = qb * 32;

  const u16* Qp = qh + (size_t)bh * S_LEN * DHEAD;
  const u16* Kp = kh + (size_t)bh * S_LEN * DHEAD;

  bf16x8 qf[4];
  {
    const u16* qrow = Qp + (size_t)(q0 + q_l) * DHEAD + hi * 8;
#pragma unroll
    for (int c = 0; c < 4; ++c) qf[c] = *reinterpret_cast<const bf16x8*>(qrow + c * 16);
  }

  float myinv[16];
#pragma unroll
  for (int r = 0; r < 16; ++r)
    myinv[r] = inv_g[(size_t)bh * S_LEN + q0 + (r & 3) + 8 * (r >> 2) + 4 * hi];

  const int k0w = w * 512;
  float mval[16];
#pragma unroll
  for (int t = 0; t < 16; ++t)
    mval[t] = mask[(size_t)b * S_LEN + k0w + t * 32 + q_l] * -1e9f;

  float* base = attn_out + ((size_t)bh * S_LEN + q0 + 4 * hi) * S_LEN + k0w + q_l;

  bf16x8 kc[4], kn[4];
  {
    const u16* kr0 = Kp + (size_t)(k0w + q_l) * DHEAD + hi * 8;
#pragma unroll
    for (int c = 0; c < 4; ++c) kc[c] = *reinterpret_cast<const bf16x8*>(kr0 + c * 16);
  }

#pragma unroll
  for (int t = 0; t < 16; ++t) {
    if (t < 15) {
      const u16* krow = Kp + (size_t)(k0w + (t + 1) * 32 + q_l) * DHEAD + hi * 8;
#pragma unroll
      for (int c = 0; c < 4; ++c) kn[c] = *reinterpret_cast<const bf16x8*>(krow + c * 16);
    }
    f32x16 a0, a1;
#pragma unroll
    for (int r = 0; r < 16; ++r) { a0[r] = 0.f; a1[r] = 0.f; }
    a0 = __builtin_amdgcn_mfma_f32_32x32x16_bf16(qf[0], kc[0], a0, 0, 0, 0);
    a0 = __builtin_amdgcn_mfma_f32_32x32x16_bf16(qf[1], kc[1], a0, 0, 0, 0);
    a1 = __builtin_amdgcn_mfma_f32_32x32x16_bf16(qf[2], kc[2], a1, 0, 0, 0);
    a1 = __builtin_amdgcn_mfma_f32_32x32x16_bf16(qf[3], kc[3], a1, 0, 0, 0);
#pragma unroll
    for (int r = 0; r < 16; ++r) {
      const float pv = __expf(a0[r] + a1[r] + mval[t]) * myinv[r];
      const int rr = (r & 3) + 8 * (r >> 2);
      __builtin_nontemporal_store(pv, &base[(size_t)rr * S_LEN + t * 32]);
    }
#pragma unroll
    for (int c = 0; c < 4; ++c) kc[c] = kn[c];
  }
}

extern "C" void kernel_launch(void* const* d_in, const int* in_sizes, int n_in,
                              void* d_out, int out_size, void* d_ws, size_t ws_size,
                              hipStream_t stream)
{
  (void)in_sizes; (void)n_in; (void)out_size; (void)ws_size;
  const float* v    = (const float*)d_in[0];
  const float* k    = (const float*)d_in[1];
  const float* q    = (const float*)d_in[2];
  const float* mask = (const float*)d_in[3];
  const float* Wq   = (const float*)d_in[4];
  const float* bq   = (const float*)d_in[5];
  const float* Wk   = (const float*)d_in[6];
  const float* bk   = (const float*)d_in[7];
  const float* Wv   = (const float*)d_in[8];
  const float* bv   = (const float*)d_in[9];
  const float* Wo   = (const float*)d_in[10];
  const float* bo   = (const float*)d_in[11];

  u16* ws16 = (u16*)d_ws;
  u16* xq  = ws16;
  u16* xk  = ws16 + (size_t)1 * NE;
  u16* xv  = ws16 + (size_t)2 * NE;
  u16* qh  = ws16 + (size_t)3 * NE;
  u16* kh  = ws16 + (size_t)4 * NE;
  u16* vh  = ws16 + (size_t)5 * NE;
  u16* wqt = ws16 + (size_t)6 * NE;
  u16* wkt = wqt + WN;
  u16* wvt = wkt + WN;
  u16* wot = wvt + WN;
  float* inv_g = (float*)(wot + WN);   // 32*2048 f32 = 256 KB
  u16* vt  = xq;   // alias: xq dead after gemm_qkv
  u16* ctx = xk;   // alias: xk dead after gemm_qkv

  float* outp  = (float*)d_out;
  float* attnp = outp + (size_t)NE;

  cvt_inputs<<<dim3(1024), dim3(256), 0, stream>>>(q, k, v, xq, xk, xv);
  wtrans<<<dim3(16, 16, 4), dim3(256), 0, stream>>>(Wq, Wk, Wv, Wo, wqt, wkt, wvt, wot);
  gemm_qkv<<<dim3(8, 32, 3), dim3(256), 0, stream>>>(xq, xk, xv, wqt, wkt, wvt,
                                                     bq, bk, bv, qh, kh, vh);
  vtrans<<<dim3(1024), dim3(256), 0, stream>>>(vh, vt);
  attn_pv<<<dim3(2048), dim3(64), 0, stream>>>(qh, kh, vt, mask, inv_g, ctx);
  tail_fused<<<dim3(2304), dim3(256), 0, stream>>>(ctx, wot, bo, outp,
                                                   qh, kh, mask, inv_g, attnp);
}